// Round 1
// baseline (757.776 us; speedup 1.0000x reference)
//
#include <hip/hip_runtime.h>
#include <hip/hip_bf16.h>

// Swin block: B=32, HW=56, C=128, WS=7, SS=3, NH=4, HD=32
// G=8 windows/side, NWIN=64, N=49 tokens/window, Bw=2048, NTOK=100352
#define NTOK 100352
#define BW 2048
#define SCALE_Q 0.17677669529663687f  // 32^-0.5

// window-token (wt = w*49+n) -> original flat token index in x
__device__ __forceinline__ int wt_to_tok(int wt) {
  int w = wt / 49, n = wt - w * 49;
  int b = w >> 6, wi = w & 63;
  int gh = wi >> 3, gw = wi & 7;
  int r = n / 7, c = n - r * 7;
  int hs = gh * 7 + r + 3; if (hs >= 56) hs -= 56;   // undo roll(-3)
  int ws = gw * 7 + c + 3; if (ws >= 56) ws -= 56;
  return (b * 56 + hs) * 56 + ws;
}

// per-token LayerNorm stats: stats[t] = (mu, rstd)
__global__ __launch_bounds__(256) void ln_stats(const float* __restrict__ x,
                                                float* __restrict__ stats) {
  int t = blockIdx.x * 4 + (threadIdx.x >> 6);
  int lane = threadIdx.x & 63;
  float2 v = *(const float2*)(x + (size_t)t * 128 + lane * 2);
  float s = v.x + v.y;
  float ss = v.x * v.x + v.y * v.y;
#pragma unroll
  for (int off = 32; off; off >>= 1) {
    s += __shfl_xor(s, off);
    ss += __shfl_xor(ss, off);
  }
  if (lane == 0) {
    float mu = s * (1.0f / 128.0f);
    float var = ss * (1.0f / 128.0f) - mu * mu;
    float2 o; o.x = mu; o.y = rsqrtf(var + 1e-5f);
    *(float2*)(stats + (size_t)t * 2) = o;
  }
}

// attention for one (window, head); qkv layout [wt][3][NH][HD] flat 384/token.
// Writes the head's output back into its own q-slot (only this block reads it).
__global__ __launch_bounds__(256) void attn_kernel(float* __restrict__ qkv,
                                                   const float* __restrict__ ptab) {
  int w = blockIdx.x >> 2, head = blockIdx.x & 3;
  int wi = w & 63, gh = wi >> 3, gw = wi & 7;
  __shared__ float q[49][33], k[49][33], v[49][33];
  __shared__ float s[49][52];
  int tid = threadIdx.x;
  for (int idx = tid; idx < 49 * 32; idx += 256) {
    int n = idx >> 5, d = idx & 31;
    int base = (w * 49 + n) * 384 + head * 32 + d;
    q[n][d] = qkv[base] * SCALE_Q;
    k[n][d] = qkv[base + 128];
    v[n][d] = qkv[base + 256];
  }
  __syncthreads();
  // scores + relative position bias + shift mask (computed analytically)
  for (int idx = tid; idx < 49 * 49; idx += 256) {
    int i = idx / 49, j = idx - i * 49;
    float acc = 0.0f;
#pragma unroll
    for (int d = 0; d < 32; ++d) acc = fmaf(q[i][d], k[j][d], acc);
    int ri = i / 7, ci = i - ri * 7, rj = j / 7, cj = j - rj * 7;
    acc += ptab[((ri - rj + 6) * 13 + (ci - cj + 6)) * 4 + head];
    int hi = gh * 7 + ri, wwi = gw * 7 + ci;
    int hj = gh * 7 + rj, wwj = gw * 7 + cj;
    int cnti = (hi < 49 ? 0 : (hi < 53 ? 3 : 6)) + (wwi < 49 ? 0 : (wwi < 53 ? 1 : 2));
    int cntj = (hj < 49 ? 0 : (hj < 53 ? 3 : 6)) + (wwj < 49 ? 0 : (wwj < 53 ? 1 : 2));
    if (cnti != cntj) acc -= 100.0f;
    s[i][j] = acc;
  }
  __syncthreads();
  // row softmax: one wave per row
  int lane = tid & 63, wid = tid >> 6;
  for (int i = wid; i < 49; i += 4) {
    float val = (lane < 49) ? s[i][lane] : -1e30f;
    float m = val;
#pragma unroll
    for (int off = 32; off; off >>= 1) m = fmaxf(m, __shfl_xor(m, off));
    float e = (lane < 49) ? expf(val - m) : 0.0f;
    float sum = e;
#pragma unroll
    for (int off = 32; off; off >>= 1) sum += __shfl_xor(sum, off);
    if (lane < 49) s[i][lane] = e / sum;
  }
  __syncthreads();
  // out = P @ V, written into this head's q-slot
  for (int idx = tid; idx < 49 * 32; idx += 256) {
    int i = idx >> 5, d = idx & 31;
    float acc = 0.0f;
#pragma unroll
    for (int j = 0; j < 49; ++j) acc = fmaf(s[i][j], v[j][d], acc);
    qkv[(w * 49 + i) * 384 + head * 32 + d] = acc;
  }
}

struct bf4 { __hip_bfloat16 x, y, z, w; };

// 64x64-tile fp32 GEMM, BK=32, 4x4 per thread.
// ASRC: 0 = LN(gather x via wt_to_tok, stats per tok), 1 = plain fp32 (lda),
//       2 = bf16 (lda), 3 = LN(direct, stats per row)
// EPI:  0 = fp32 +bias (ldo), 1 = gelu->bf16 (ldo), 2 = +bias +res[gather tok] -> out[tok],
//       3 = +bias +res[m] -> out[m]
template<int ASRC, int EPI>
__global__ __launch_bounds__(256) void gemm64(
    const void* __restrict__ Av, int lda,
    const float* __restrict__ W, int ldw,
    const float* __restrict__ bias,
    void* __restrict__ outv, int ldo,
    const float* __restrict__ stats,
    const float* __restrict__ nw, const float* __restrict__ nb,
    const float* __restrict__ res, int K)
{
  __shared__ __align__(16) float AsT[32][64];  // [k][row]
  __shared__ __align__(16) float Ws[32][64];   // [k][col]
  int m0 = blockIdx.x * 64, n0 = blockIdx.y * 64;
  int tid = threadIdx.x;
  int tx = tid & 15, ty = tid >> 4;
  int ar = tid >> 2, ac = (tid & 3) * 8;
  int wk = tid >> 4, wn = (tid & 15) * 4;
  float acc[4][4] = {};
  int am = m0 + ar;

  for (int k0 = 0; k0 < K; k0 += 32) {
    // ---- A tile (transposed into LDS) ----
    if (ASRC == 0 || ASRC == 3) {
      int tok = (ASRC == 0) ? wt_to_tok(am) : am;
      float2 st = *(const float2*)(stats + (size_t)tok * 2);
      const float* xr = (const float*)Av + (size_t)tok * 128 + k0 + ac;
      float xv[8], wv[8], bv[8];
      *(float4*)&xv[0] = *(const float4*)xr;
      *(float4*)&xv[4] = *(const float4*)(xr + 4);
      *(float4*)&wv[0] = *(const float4*)(nw + k0 + ac);
      *(float4*)&wv[4] = *(const float4*)(nw + k0 + ac + 4);
      *(float4*)&bv[0] = *(const float4*)(nb + k0 + ac);
      *(float4*)&bv[4] = *(const float4*)(nb + k0 + ac + 4);
#pragma unroll
      for (int qq = 0; qq < 8; ++qq)
        AsT[ac + qq][ar] = (xv[qq] - st.x) * st.y * wv[qq] + bv[qq];
    } else if (ASRC == 1) {
      const float* ap = (const float*)Av + (size_t)am * lda + k0 + ac;
      float xv[8];
      *(float4*)&xv[0] = *(const float4*)ap;
      *(float4*)&xv[4] = *(const float4*)(ap + 4);
#pragma unroll
      for (int qq = 0; qq < 8; ++qq) AsT[ac + qq][ar] = xv[qq];
    } else {
      const __hip_bfloat16* ap = (const __hip_bfloat16*)Av + (size_t)am * lda + k0 + ac;
      int4 raw = *(const int4*)ap;
      const unsigned short* us = (const unsigned short*)&raw;
#pragma unroll
      for (int qq = 0; qq < 8; ++qq) {
        union { unsigned int u; float f; } cv;
        cv.u = ((unsigned int)us[qq]) << 16;
        AsT[ac + qq][ar] = cv.f;
      }
    }
    // ---- W tile ----
#pragma unroll
    for (int h = 0; h < 2; ++h) {
      int kk = wk + h * 16;
      *(float4*)&Ws[kk][wn] = *(const float4*)(W + (size_t)(k0 + kk) * ldw + n0 + wn);
    }
    __syncthreads();
#pragma unroll
    for (int kk = 0; kk < 32; ++kk) {
      float4 a4 = *(const float4*)&AsT[kk][ty * 4];
      float4 b4 = *(const float4*)&Ws[kk][tx * 4];
      float av[4] = {a4.x, a4.y, a4.z, a4.w};
      float bv2[4] = {b4.x, b4.y, b4.z, b4.w};
#pragma unroll
      for (int i = 0; i < 4; ++i)
#pragma unroll
        for (int j = 0; j < 4; ++j)
          acc[i][j] = fmaf(av[i], bv2[j], acc[i][j]);
    }
    __syncthreads();
  }

  // ---- epilogue ----
  int nc = n0 + tx * 4;
  float4 bs = *(const float4*)(bias + nc);
  float bb[4] = {bs.x, bs.y, bs.z, bs.w};
#pragma unroll
  for (int i = 0; i < 4; ++i) {
    int m = m0 + ty * 4 + i;
    if (EPI == 0) {
      float4 o;
      o.x = acc[i][0] + bb[0]; o.y = acc[i][1] + bb[1];
      o.z = acc[i][2] + bb[2]; o.w = acc[i][3] + bb[3];
      *(float4*)((float*)outv + (size_t)m * ldo + nc) = o;
    } else if (EPI == 1) {
      float vv[4];
#pragma unroll
      for (int j = 0; j < 4; ++j) {
        float val = acc[i][j] + bb[j];
        vv[j] = 0.5f * val * (1.0f + erff(val * 0.70710678118654752f));
      }
      bf4 o;
      o.x = __float2bfloat16(vv[0]); o.y = __float2bfloat16(vv[1]);
      o.z = __float2bfloat16(vv[2]); o.w = __float2bfloat16(vv[3]);
      *(bf4*)((__hip_bfloat16*)outv + (size_t)m * ldo + nc) = o;
    } else if (EPI == 2) {
      int tok = wt_to_tok(m);
      float4 r4 = *(const float4*)(res + (size_t)tok * 128 + nc);
      float4 o;
      o.x = acc[i][0] + bb[0] + r4.x; o.y = acc[i][1] + bb[1] + r4.y;
      o.z = acc[i][2] + bb[2] + r4.z; o.w = acc[i][3] + bb[3] + r4.w;
      *(float4*)((float*)outv + (size_t)tok * 128 + nc) = o;
    } else {
      float4 r4 = *(const float4*)(res + (size_t)m * 128 + nc);
      float4 o;
      o.x = acc[i][0] + bb[0] + r4.x; o.y = acc[i][1] + bb[1] + r4.y;
      o.z = acc[i][2] + bb[2] + r4.z; o.w = acc[i][3] + bb[3] + r4.w;
      *(float4*)((float*)outv + (size_t)m * 128 + nc) = o;
    }
  }
}

extern "C" void kernel_launch(void* const* d_in, const int* in_sizes, int n_in,
                              void* d_out, int out_size, void* d_ws, size_t ws_size,
                              hipStream_t stream) {
  (void)in_sizes; (void)n_in; (void)out_size; (void)ws_size;
  const float* x     = (const float*)d_in[0];
  const float* n1w   = (const float*)d_in[1];
  const float* n1b   = (const float*)d_in[2];
  const float* qkvw  = (const float*)d_in[3];
  const float* qkvb  = (const float*)d_in[4];
  const float* projw = (const float*)d_in[5];
  const float* projb = (const float*)d_in[6];
  const float* ptab  = (const float*)d_in[7];
  const float* w1    = (const float*)d_in[8];
  const float* b1    = (const float*)d_in[9];
  const float* w2    = (const float*)d_in[10];
  const float* b2    = (const float*)d_in[11];
  const float* n2w   = (const float*)d_in[12];
  const float* n2b   = (const float*)d_in[13];
  float* out = (float*)d_out;

  // workspace layout (207,126,528 bytes total):
  //   [0, 154140672)           qkv fp32 [2048*49][384]; attn-out aliased into q-slots;
  //                            later reused as u bf16 [100352][512] (102,760,448 B)
  //   [154140672, 205520896)   x2 fp32 [100352][128]
  //   [205520896, 206323712)   stats1 (mu,rstd per token)
  //   [206323712, 207126528)   stats2
  char* ws = (char*)d_ws;
  float* qkv = (float*)ws;
  __hip_bfloat16* u = (__hip_bfloat16*)ws;
  float* x2  = (float*)(ws + 154140672);
  float* st1 = (float*)(ws + 205520896);
  float* st2 = (float*)(ws + 206323712);

  // 1) LN1 stats
  ln_stats<<<NTOK / 4, 256, 0, stream>>>(x, st1);
  // 2) qkv = LN1(x)[gathered to window order] @ qkv_w + qkv_b
  gemm64<0, 0><<<dim3(1568, 6), 256, 0, stream>>>(x, 128, qkvw, 384, qkvb,
                                                  qkv, 384, st1, n1w, n1b, nullptr, 128);
  // 3) windowed attention (bias + shift mask analytic), out -> q-slots
  attn_kernel<<<BW * 4, 256, 0, stream>>>(qkv, ptab);
  // 4) x2[tok] = x[tok] + attn_out @ proj_w + proj_b   (window reverse + roll fused)
  gemm64<1, 2><<<dim3(1568, 2), 256, 0, stream>>>(qkv, 384, projw, 128, projb,
                                                  x2, 128, nullptr, nullptr, nullptr, x, 128);
  // 5) LN2 stats
  ln_stats<<<NTOK / 4, 256, 0, stream>>>(x2, st2);
  // 6) u = gelu(LN2(x2) @ w1 + b1)  (bf16, aliases dead qkv region)
  gemm64<3, 1><<<dim3(1568, 8), 256, 0, stream>>>(x2, 128, w1, 512, b1,
                                                  (void*)u, 512, st2, n2w, n2b, nullptr, 128);
  // 7) out = x2 + u @ w2 + b2
  gemm64<2, 3><<<dim3(1568, 2), 256, 0, stream>>>(u, 512, w2, 128, b2,
                                                  out, 128, nullptr, nullptr, nullptr, x2, 512);
}

// Round 2
// 454.138 us; speedup vs baseline: 1.6686x; 1.6686x over previous
//
#include <hip/hip_runtime.h>
#include <hip/hip_bf16.h>

// Swin block: B=32, HW=56, C=128, WS=7, SS=3, NH=4, HD=32
#define NTOK 100352
#define SCALE_Q 0.17677669529663687f  // 32^-0.5

typedef __bf16 bf16x8 __attribute__((ext_vector_type(8)));
typedef float f32x4 __attribute__((ext_vector_type(4)));

// window-token (wt = w*49+n) -> original flat token index in x
__device__ __forceinline__ int wt_to_tok(int wt) {
  int w = wt / 49, n = wt - w * 49;
  int b = w >> 6, wi = w & 63;
  int gh = wi >> 3, gw = wi & 7;
  int r = n / 7, c = n - r * 7;
  int hs = gh * 7 + r + 3; if (hs >= 56) hs -= 56;   // undo roll(-3)
  int ws = gw * 7 + c + 3; if (ws >= 56) ws -= 56;
  return (b * 56 + hs) * 56 + ws;
}

// per-token LayerNorm stats: stats[t] = (mu, rstd)
__global__ __launch_bounds__(256) void ln_stats(const float* __restrict__ x,
                                                float* __restrict__ stats) {
  int t = blockIdx.x * 4 + (threadIdx.x >> 6);
  int lane = threadIdx.x & 63;
  float2 v = *(const float2*)(x + (size_t)t * 128 + lane * 2);
  float s = v.x + v.y;
  float ss = v.x * v.x + v.y * v.y;
#pragma unroll
  for (int off = 32; off; off >>= 1) {
    s += __shfl_xor(s, off);
    ss += __shfl_xor(ss, off);
  }
  if (lane == 0) {
    float mu = s * (1.0f / 128.0f);
    float var = ss * (1.0f / 128.0f) - mu * mu;
    float2 o; o.x = mu; o.y = rsqrtf(var + 1e-5f);
    *(float2*)(stats + (size_t)t * 2) = o;
  }
}

// weight transpose + bf16: dst[n*K+k] = bf16(src[k*N+n])
__global__ __launch_bounds__(256) void prep_w(const float* __restrict__ src,
                                              __hip_bfloat16* __restrict__ dst,
                                              int K, int N) {
  int i = blockIdx.x * 256 + threadIdx.x;
  if (i >= K * N) return;
  int n = i / K, k = i - n * K;
  dst[i] = __float2bfloat16(src[(size_t)k * N + n]);
}

// attention for one (window, head); qkv bf16 layout [wt][384].
// Writes the head's output back into its own q-slot (only this block touches it).
__global__ __launch_bounds__(256) void attn_kernel(__hip_bfloat16* __restrict__ qkv,
                                                   const float* __restrict__ ptab) {
  int w = blockIdx.x >> 2, head = blockIdx.x & 3;
  int wi = w & 63, gh = wi >> 3, gw = wi & 7;
  __shared__ float q[49][33], k[49][33], v[49][33];
  __shared__ float s[49][52];
  int tid = threadIdx.x;
  for (int idx = tid; idx < 49 * 32; idx += 256) {
    int n = idx >> 5, d = idx & 31;
    int base = (w * 49 + n) * 384 + head * 32 + d;
    q[n][d] = __bfloat162float(qkv[base]) * SCALE_Q;
    k[n][d] = __bfloat162float(qkv[base + 128]);
    v[n][d] = __bfloat162float(qkv[base + 256]);
  }
  __syncthreads();
  for (int idx = tid; idx < 49 * 49; idx += 256) {
    int i = idx / 49, j = idx - i * 49;
    float acc = 0.0f;
#pragma unroll
    for (int d = 0; d < 32; ++d) acc = fmaf(q[i][d], k[j][d], acc);
    int ri = i / 7, ci = i - ri * 7, rj = j / 7, cj = j - rj * 7;
    acc += ptab[((ri - rj + 6) * 13 + (ci - cj + 6)) * 4 + head];
    int hi = gh * 7 + ri, wwi = gw * 7 + ci;
    int hj = gh * 7 + rj, wwj = gw * 7 + cj;
    int cnti = (hi < 49 ? 0 : (hi < 53 ? 3 : 6)) + (wwi < 49 ? 0 : (wwi < 53 ? 1 : 2));
    int cntj = (hj < 49 ? 0 : (hj < 53 ? 3 : 6)) + (wwj < 49 ? 0 : (wwj < 53 ? 1 : 2));
    if (cnti != cntj) acc -= 100.0f;
    s[i][j] = acc;
  }
  __syncthreads();
  int lane = tid & 63, wid = tid >> 6;
  for (int i = wid; i < 49; i += 4) {
    float val = (lane < 49) ? s[i][lane] : -1e30f;
    float m = val;
#pragma unroll
    for (int off = 32; off; off >>= 1) m = fmaxf(m, __shfl_xor(m, off));
    float e = (lane < 49) ? expf(val - m) : 0.0f;
    float sum = e;
#pragma unroll
    for (int off = 32; off; off >>= 1) sum += __shfl_xor(sum, off);
    if (lane < 49) s[i][lane] = e / sum;
  }
  __syncthreads();
  for (int idx = tid; idx < 49 * 32; idx += 256) {
    int i = idx >> 5, d = idx & 31;
    float acc = 0.0f;
#pragma unroll
    for (int j = 0; j < 49; ++j) acc = fmaf(s[i][j], v[j][d], acc);
    qkv[(w * 49 + i) * 384 + head * 32 + d] = __float2bfloat16(acc);
  }
}

// ---------------------------------------------------------------------------
// MFMA bf16 GEMM: 128x128 tile, BK=128, 256 threads (4 waves, 2x2 of 64x64).
// A: [M][K] activations; B^T: [N][K] bf16 (pre-transposed weights).
// ASRC: 0 = LN(gather x via wt_to_tok), 1 = LN(direct), 2 = bf16 direct (lda)
// EPI:  0 = +bias -> bf16 (ldo), 1 = gelu -> bf16 (ldo),
//       2 = +bias +res, out/res indexed by wt_to_tok (fp32, stride 128),
//       3 = +bias +res direct (fp32, stride 128)
// LDS swizzle: byte_in_row ^= (row&7)<<4  (applies to both write and read)
// ---------------------------------------------------------------------------
template<int ASRC, int EPI>
__global__ __launch_bounds__(256) void gemm_mfma(
    const void* __restrict__ Av, int lda,
    const __hip_bfloat16* __restrict__ Wt,
    const float* __restrict__ bias,
    void* __restrict__ outv, int ldo,
    const float* __restrict__ stats,
    const float* __restrict__ nw, const float* __restrict__ nb,
    const float* __restrict__ res, int K)
{
  __shared__ __align__(16) char AsB[128 * 256];
  __shared__ __align__(16) char BsB[128 * 256];
  const int tid = threadIdx.x;
  const int m0 = blockIdx.x * 128, n0 = blockIdx.y * 128;
  const int srow = tid >> 1;             // staging row 0..127
  const int scol = (tid & 1) * 64;       // staging col (elements)
  const int lane = tid & 63, wid = tid >> 6;
  const int wm = wid >> 1, wn = wid & 1;
  const int lrow = lane & 15, lq = lane >> 4;

  f32x4 acc[4][4] = {};

  for (int k0 = 0; k0 < K; k0 += 128) {
    // ---- stage A tile ----
    if (ASRC == 2) {
      const char* ap = (const char*)Av + ((size_t)(m0 + srow) * lda + k0 + scol) * 2;
      char* dst = AsB + srow * 256;
      int sw = (srow & 7) << 4;
#pragma unroll
      for (int t = 0; t < 8; ++t) {
        int4 raw = *(const int4*)(ap + t * 16);
        *(int4*)(dst + ((scol * 2 + t * 16) ^ sw)) = raw;
      }
    } else {
      int m = m0 + srow;
      int tok = (ASRC == 0) ? wt_to_tok(m) : m;
      float2 st = *(const float2*)(stats + (size_t)tok * 2);
      const float* xr = (const float*)Av + (size_t)tok * 128 + k0 + scol;
      const float* wr = nw + k0 + scol;
      const float* br = nb + k0 + scol;
      char* dst = AsB + srow * 256;
      int sw = (srow & 7) << 4;
#pragma unroll
      for (int t = 0; t < 8; ++t) {
        float4 x0 = *(const float4*)(xr + t * 8);
        float4 x1 = *(const float4*)(xr + t * 8 + 4);
        float4 w0 = *(const float4*)(wr + t * 8);
        float4 w1 = *(const float4*)(wr + t * 8 + 4);
        float4 b0 = *(const float4*)(br + t * 8);
        float4 b1 = *(const float4*)(br + t * 8 + 4);
        float xv[8] = {x0.x, x0.y, x0.z, x0.w, x1.x, x1.y, x1.z, x1.w};
        float wv[8] = {w0.x, w0.y, w0.z, w0.w, w1.x, w1.y, w1.z, w1.w};
        float bv[8] = {b0.x, b0.y, b0.z, b0.w, b1.x, b1.y, b1.z, b1.w};
        union { int4 i4; __hip_bfloat16 h[8]; } u;
#pragma unroll
        for (int q = 0; q < 8; ++q)
          u.h[q] = __float2bfloat16((xv[q] - st.x) * st.y * wv[q] + bv[q]);
        *(int4*)(dst + ((scol * 2 + t * 16) ^ sw)) = u.i4;
      }
    }
    // ---- stage B^T tile ----
    {
      const char* bp = (const char*)Wt + ((size_t)(n0 + srow) * K + k0 + scol) * 2;
      char* dst = BsB + srow * 256;
      int sw = (srow & 7) << 4;
#pragma unroll
      for (int t = 0; t < 8; ++t) {
        int4 raw = *(const int4*)(bp + t * 16);
        *(int4*)(dst + ((scol * 2 + t * 16) ^ sw)) = raw;
      }
    }
    __syncthreads();
    // ---- MFMA: 4 k-steps of 32 ----
#pragma unroll
    for (int ks = 0; ks < 4; ++ks) {
      int kb = ks * 64 + lq * 16;  // byte offset of this lane's 8 bf16 in k
      bf16x8 af[4], bfr[4];
#pragma unroll
      for (int mi = 0; mi < 4; ++mi) {
        int r = wm * 64 + mi * 16 + lrow;
        af[mi] = *(const bf16x8*)(AsB + r * 256 + (kb ^ ((r & 7) << 4)));
      }
#pragma unroll
      for (int ni = 0; ni < 4; ++ni) {
        int r = wn * 64 + ni * 16 + lrow;
        bfr[ni] = *(const bf16x8*)(BsB + r * 256 + (kb ^ ((r & 7) << 4)));
      }
#pragma unroll
      for (int mi = 0; mi < 4; ++mi)
#pragma unroll
        for (int ni = 0; ni < 4; ++ni)
          acc[mi][ni] = __builtin_amdgcn_mfma_f32_16x16x32_bf16(af[mi], bfr[ni], acc[mi][ni], 0, 0, 0);
    }
    __syncthreads();
  }

  // ---- epilogue ----
  float bv[4];
#pragma unroll
  for (int ni = 0; ni < 4; ++ni) bv[ni] = bias[n0 + wn * 64 + ni * 16 + lrow];
#pragma unroll
  for (int mi = 0; mi < 4; ++mi) {
#pragma unroll
    for (int j = 0; j < 4; ++j) {
      int rowg = m0 + wm * 64 + mi * 16 + lq * 4 + j;
      int orow = (EPI == 2) ? wt_to_tok(rowg) : rowg;
#pragma unroll
      for (int ni = 0; ni < 4; ++ni) {
        int colg = n0 + wn * 64 + ni * 16 + lrow;
        float val = acc[mi][ni][j] + bv[ni];
        if (EPI == 0) {
          ((__hip_bfloat16*)outv)[(size_t)rowg * ldo + colg] = __float2bfloat16(val);
        } else if (EPI == 1) {
          float g = 0.5f * val * (1.0f + erff(val * 0.70710678118654752f));
          ((__hip_bfloat16*)outv)[(size_t)rowg * ldo + colg] = __float2bfloat16(g);
        } else {
          float r = res[(size_t)orow * 128 + colg];
          ((float*)outv)[(size_t)orow * 128 + colg] = val + r;
        }
      }
    }
  }
}

extern "C" void kernel_launch(void* const* d_in, const int* in_sizes, int n_in,
                              void* d_out, int out_size, void* d_ws, size_t ws_size,
                              hipStream_t stream) {
  (void)in_sizes; (void)n_in; (void)out_size; (void)ws_size;
  const float* x     = (const float*)d_in[0];
  const float* n1w   = (const float*)d_in[1];
  const float* n1b   = (const float*)d_in[2];
  const float* qkvw  = (const float*)d_in[3];
  const float* qkvb  = (const float*)d_in[4];
  const float* projw = (const float*)d_in[5];
  const float* projb = (const float*)d_in[6];
  const float* ptab  = (const float*)d_in[7];
  const float* w1    = (const float*)d_in[8];
  const float* b1    = (const float*)d_in[9];
  const float* w2    = (const float*)d_in[10];
  const float* b2    = (const float*)d_in[11];
  const float* n2w   = (const float*)d_in[12];
  const float* n2b   = (const float*)d_in[13];
  float* out = (float*)d_out;

  // workspace layout:
  //   [0, 102760448)            qkv bf16 [100352][384] (77MB); later u bf16 [100352][512] (103MB)
  //   [102760448, 154140672)    x2 fp32 [100352][128]
  //   [154140672, +802816)      stats1
  //   [154943488, +802816)      stats2
  //   [155746304, ...)          transposed bf16 weights
  char* ws = (char*)d_ws;
  __hip_bfloat16* qkv = (__hip_bfloat16*)ws;
  __hip_bfloat16* u   = (__hip_bfloat16*)ws;
  float* x2  = (float*)(ws + 102760448);
  float* st1 = (float*)(ws + 154140672);
  float* st2 = (float*)(ws + 154943488);
  __hip_bfloat16* qkvwT = (__hip_bfloat16*)(ws + 155746304);             // [384][128]
  __hip_bfloat16* projwT = (__hip_bfloat16*)(ws + 155746304 + 98304);    // [128][128]
  __hip_bfloat16* w1T = (__hip_bfloat16*)(ws + 155746304 + 131072);      // [512][128]
  __hip_bfloat16* w2T = (__hip_bfloat16*)(ws + 155746304 + 262144);      // [128][512]

  prep_w<<<(384 * 128 + 255) / 256, 256, 0, stream>>>(qkvw, qkvwT, 128, 384);
  prep_w<<<(128 * 128 + 255) / 256, 256, 0, stream>>>(projw, projwT, 128, 128);
  prep_w<<<(512 * 128 + 255) / 256, 256, 0, stream>>>(w1, w1T, 128, 512);
  prep_w<<<(128 * 512 + 255) / 256, 256, 0, stream>>>(w2, w2T, 512, 128);

  ln_stats<<<NTOK / 4, 256, 0, stream>>>(x, st1);
  // qkv = LN1(x)[window order] @ qkv_w + qkv_b   (bf16 out)
  gemm_mfma<0, 0><<<dim3(784, 3), 256, 0, stream>>>(x, 128, qkvwT, qkvb,
                                                    qkv, 384, st1, n1w, n1b, nullptr, 128);
  attn_kernel<<<8192, 256, 0, stream>>>(qkv, ptab);
  // x2[tok] = x[tok] + attn_out @ proj_w + proj_b
  gemm_mfma<2, 2><<<dim3(784, 1), 256, 0, stream>>>(qkv, 384, projwT, projb,
                                                    x2, 128, nullptr, nullptr, nullptr, x, 128);
  ln_stats<<<NTOK / 4, 256, 0, stream>>>(x2, st2);
  // u = gelu(LN2(x2) @ w1 + b1)   (bf16, aliases dead qkv region)
  gemm_mfma<1, 1><<<dim3(784, 4), 256, 0, stream>>>(x2, 128, w1T, b1,
                                                    (void*)u, 512, st2, n2w, n2b, nullptr, 128);
  // out = x2 + u @ w2 + b2
  gemm_mfma<2, 3><<<dim3(784, 1), 256, 0, stream>>>(u, 512, w2T, b2,
                                                    out, 128, nullptr, nullptr, nullptr, x2, 512);
}

// Round 3
// 323.119 us; speedup vs baseline: 2.3452x; 1.4055x over previous
//
#include <hip/hip_runtime.h>
#include <hip/hip_bf16.h>

// Swin block: B=32, HW=56, C=128, WS=7, SS=3, NH=4, HD=32
#define NTOK 100352
#define SCALE_Q 0.17677669529663687f  // 32^-0.5

typedef __bf16 bf16x8 __attribute__((ext_vector_type(8)));
typedef float f32x4 __attribute__((ext_vector_type(4)));

// window-token (wt = w*49+n) -> original flat token index in x
__device__ __forceinline__ int wt_to_tok(int wt) {
  int w = wt / 49, n = wt - w * 49;
  int b = w >> 6, wi = w & 63;
  int gh = wi >> 3, gw = wi & 7;
  int r = n / 7, c = n - r * 7;
  int hs = gh * 7 + r + 3; if (hs >= 56) hs -= 56;   // undo roll(-3)
  int ws = gw * 7 + c + 3; if (ws >= 56) ws -= 56;
  return (b * 56 + hs) * 56 + ws;
}

// per-token LayerNorm stats: stats[t] = (mu, rstd)
__global__ __launch_bounds__(256) void ln_stats(const float* __restrict__ x,
                                                float* __restrict__ stats) {
  int t = blockIdx.x * 4 + (threadIdx.x >> 6);
  int lane = threadIdx.x & 63;
  float2 v = *(const float2*)(x + (size_t)t * 128 + lane * 2);
  float s = v.x + v.y;
  float ss = v.x * v.x + v.y * v.y;
#pragma unroll
  for (int off = 32; off; off >>= 1) {
    s += __shfl_xor(s, off);
    ss += __shfl_xor(ss, off);
  }
  if (lane == 0) {
    float mu = s * (1.0f / 128.0f);
    float var = ss * (1.0f / 128.0f) - mu * mu;
    float2 o; o.x = mu; o.y = rsqrtf(var + 1e-5f);
    *(float2*)(stats + (size_t)t * 2) = o;
  }
}

// weight transpose + bf16: dst[n*K+k] = bf16(src[k*N+n])
__global__ __launch_bounds__(256) void prep_w(const float* __restrict__ src,
                                              __hip_bfloat16* __restrict__ dst,
                                              int K, int N) {
  int i = blockIdx.x * 256 + threadIdx.x;
  if (i >= K * N) return;
  int n = i / K, k = i - n * K;
  dst[i] = __float2bfloat16(src[(size_t)k * N + n]);
}

// ---------------------------------------------------------------------------
// MFMA attention: 1 block = 1 window, wave w = head w. 49 tokens padded to 64.
// qkv bf16 [wt][384]; output written into the head's q-slot.
// Per-wave LDS: P [64][128B] XOR-swizzled + VT [32][128B] XOR-swizzled.
// ---------------------------------------------------------------------------
__global__ __launch_bounds__(256) void attn_mfma(__hip_bfloat16* __restrict__ qkv,
                                                 const float* __restrict__ ptab) {
  __shared__ __align__(16) char lds[4 * 12288];
  const int tid = threadIdx.x;
  const int lane = tid & 63, h = tid >> 6;
  const int w = blockIdx.x;
  const int wi = w & 63, gh = wi >> 3, gw = wi & 7;
  char* Pl = lds + h * 12288;
  char* VTl = Pl + 8192;
  const int lxi = lane & 15, lq = lane >> 4, lg4 = (lane >> 4) * 4;

  __hip_bfloat16* base = qkv + (size_t)w * 49 * 384 + h * 32;

  // ---- load Q/K fragments directly from global (clamped tokens) ----
  bf16x8 qa[4], kb[4];
#pragma unroll
  for (int mi = 0; mi < 4; ++mi) {
    int t = mi * 16 + lxi; if (t > 48) t = 48;
    qa[mi] = *(const bf16x8*)(base + (size_t)t * 384 + lq * 8);
    kb[mi] = *(const bf16x8*)(base + (size_t)t * 384 + 128 + lq * 8);
  }

  // ---- stage VT[dim][token] (zero token cols >= 49; LDS is uninitialized) ----
  {
    union { bf16x8 v; __hip_bfloat16 e[8]; } vv[4];
    const __hip_bfloat16* vp = base + (size_t)(lane < 49 ? lane : 0) * 384 + 256;
#pragma unroll
    for (int q = 0; q < 4; ++q) vv[q].v = *(const bf16x8*)(vp + q * 8);
    __hip_bfloat16 z = __float2bfloat16(0.0f);
#pragma unroll
    for (int q = 0; q < 4; ++q)
#pragma unroll
      for (int e = 0; e < 8; ++e) {
        int d = q * 8 + e;
        __hip_bfloat16 val = (lane < 49) ? vv[q].e[e] : z;
        *(__hip_bfloat16*)(VTl + d * 128 + ((lane * 2) ^ ((d & 7) << 4))) = val;
      }
  }

  // ---- S = Q @ K^T ----
  f32x4 s[4][4] = {};
#pragma unroll
  for (int mi = 0; mi < 4; ++mi)
#pragma unroll
    for (int ni = 0; ni < 4; ++ni)
      s[mi][ni] = __builtin_amdgcn_mfma_f32_16x16x32_bf16(qa[mi], kb[ni], s[mi][ni], 0, 0, 0);

  // ---- scale + relative position bias + shift mask (analytic) ----
  int rj[4], cj[4], cntj[4], jbad[4];
#pragma unroll
  for (int ni = 0; ni < 4; ++ni) {
    int jc = ni * 16 + lxi;
    jbad[ni] = (jc > 48);
    int jj = jbad[ni] ? 48 : jc;
    rj[ni] = jj / 7; cj[ni] = jj - rj[ni] * 7;
    int hj = gh * 7 + rj[ni], wj = gw * 7 + cj[ni];
    cntj[ni] = (hj < 49 ? 0 : (hj < 53 ? 3 : 6)) + (wj < 49 ? 0 : (wj < 53 ? 1 : 2));
  }
#pragma unroll
  for (int mi = 0; mi < 4; ++mi)
#pragma unroll
    for (int j = 0; j < 4; ++j) {
      int i = mi * 16 + lg4 + j; if (i > 48) i = 48;
      int ri = i / 7, ci = i - ri * 7;
      int hi_ = gh * 7 + ri, wi_ = gw * 7 + ci;
      int cnti = (hi_ < 49 ? 0 : (hi_ < 53 ? 3 : 6)) + (wi_ < 49 ? 0 : (wi_ < 53 ? 1 : 2));
#pragma unroll
      for (int ni = 0; ni < 4; ++ni) {
        float b = ptab[((ri - rj[ni] + 6) * 13 + (ci - cj[ni] + 6)) * 4 + h];
        float val = s[mi][ni][j] * SCALE_Q + b;
        if (cnti != cntj[ni]) val -= 100.0f;
        if (jbad[ni]) val = -1e30f;
        s[mi][ni][j] = val;
      }
    }

  // ---- in-register row softmax (row = mi*16 + lg4 + j; 16-lane butterfly) ----
#pragma unroll
  for (int mi = 0; mi < 4; ++mi)
#pragma unroll
    for (int j = 0; j < 4; ++j) {
      float m = fmaxf(fmaxf(s[mi][0][j], s[mi][1][j]), fmaxf(s[mi][2][j], s[mi][3][j]));
#pragma unroll
      for (int off = 8; off; off >>= 1) m = fmaxf(m, __shfl_xor(m, off));
      float e[4], sum = 0.0f;
#pragma unroll
      for (int ni = 0; ni < 4; ++ni) { e[ni] = __expf(s[mi][ni][j] - m); sum += e[ni]; }
#pragma unroll
      for (int off = 8; off; off >>= 1) sum += __shfl_xor(sum, off);
      float inv = 1.0f / sum;
#pragma unroll
      for (int ni = 0; ni < 4; ++ni) s[mi][ni][j] = e[ni] * inv;
    }

  // ---- P -> LDS (bf16, XOR-swizzled) ----
#pragma unroll
  for (int mi = 0; mi < 4; ++mi)
#pragma unroll
    for (int j = 0; j < 4; ++j) {
      int row = mi * 16 + lg4 + j;
      int sw = (row & 7) << 4;
      char* prow = Pl + row * 128;
#pragma unroll
      for (int ni = 0; ni < 4; ++ni)
        *(__hip_bfloat16*)(prow + (((ni * 16 + lxi) * 2) ^ sw)) =
            __float2bfloat16(s[mi][ni][j]);
    }

  __syncthreads();

  // ---- O = P @ V via VT ----
  f32x4 o[4][2] = {};
#pragma unroll
  for (int ks = 0; ks < 2; ++ks) {
    bf16x8 pa[4], vb[2];
#pragma unroll
    for (int mi = 0; mi < 4; ++mi) {
      int row = mi * 16 + lxi;
      pa[mi] = *(const bf16x8*)(Pl + row * 128 + ((ks * 64 + lq * 16) ^ ((row & 7) << 4)));
    }
#pragma unroll
    for (int ni = 0; ni < 2; ++ni) {
      int row = ni * 16 + lxi;
      vb[ni] = *(const bf16x8*)(VTl + row * 128 + ((ks * 64 + lq * 16) ^ ((row & 7) << 4)));
    }
#pragma unroll
    for (int mi = 0; mi < 4; ++mi)
#pragma unroll
      for (int ni = 0; ni < 2; ++ni)
        o[mi][ni] = __builtin_amdgcn_mfma_f32_16x16x32_bf16(pa[mi], vb[ni], o[mi][ni], 0, 0, 0);
  }

  // ---- store O into this head's q-slot ----
#pragma unroll
  for (int mi = 0; mi < 4; ++mi)
#pragma unroll
    for (int j = 0; j < 4; ++j) {
      int q = mi * 16 + lg4 + j;
      if (q < 49) {
#pragma unroll
        for (int ni = 0; ni < 2; ++ni)
          base[(size_t)q * 384 + ni * 16 + lxi] = __float2bfloat16(o[mi][ni][j]);
      }
    }
}

// ---------------------------------------------------------------------------
// MFMA bf16 GEMM: 128x128 tile, BK=128, 256 threads (4 waves, 2x2 of 64x64).
// (unchanged from round 2)
// ---------------------------------------------------------------------------
template<int ASRC, int EPI>
__global__ __launch_bounds__(256) void gemm_mfma(
    const void* __restrict__ Av, int lda,
    const __hip_bfloat16* __restrict__ Wt,
    const float* __restrict__ bias,
    void* __restrict__ outv, int ldo,
    const float* __restrict__ stats,
    const float* __restrict__ nw, const float* __restrict__ nb,
    const float* __restrict__ res, int K)
{
  __shared__ __align__(16) char AsB[128 * 256];
  __shared__ __align__(16) char BsB[128 * 256];
  const int tid = threadIdx.x;
  const int m0 = blockIdx.x * 128, n0 = blockIdx.y * 128;
  const int srow = tid >> 1;
  const int scol = (tid & 1) * 64;
  const int lane = tid & 63, wid = tid >> 6;
  const int wm = wid >> 1, wn = wid & 1;
  const int lrow = lane & 15, lq = lane >> 4;

  f32x4 acc[4][4] = {};

  for (int k0 = 0; k0 < K; k0 += 128) {
    if (ASRC == 2) {
      const char* ap = (const char*)Av + ((size_t)(m0 + srow) * lda + k0 + scol) * 2;
      char* dst = AsB + srow * 256;
      int sw = (srow & 7) << 4;
#pragma unroll
      for (int t = 0; t < 8; ++t) {
        int4 raw = *(const int4*)(ap + t * 16);
        *(int4*)(dst + ((scol * 2 + t * 16) ^ sw)) = raw;
      }
    } else {
      int m = m0 + srow;
      int tok = (ASRC == 0) ? wt_to_tok(m) : m;
      float2 st = *(const float2*)(stats + (size_t)tok * 2);
      const float* xr = (const float*)Av + (size_t)tok * 128 + k0 + scol;
      const float* wr = nw + k0 + scol;
      const float* br = nb + k0 + scol;
      char* dst = AsB + srow * 256;
      int sw = (srow & 7) << 4;
#pragma unroll
      for (int t = 0; t < 8; ++t) {
        float4 x0 = *(const float4*)(xr + t * 8);
        float4 x1 = *(const float4*)(xr + t * 8 + 4);
        float4 w0 = *(const float4*)(wr + t * 8);
        float4 w1 = *(const float4*)(wr + t * 8 + 4);
        float4 b0 = *(const float4*)(br + t * 8);
        float4 b1 = *(const float4*)(br + t * 8 + 4);
        float xv[8] = {x0.x, x0.y, x0.z, x0.w, x1.x, x1.y, x1.z, x1.w};
        float wv[8] = {w0.x, w0.y, w0.z, w0.w, w1.x, w1.y, w1.z, w1.w};
        float bv[8] = {b0.x, b0.y, b0.z, b0.w, b1.x, b1.y, b1.z, b1.w};
        union { int4 i4; __hip_bfloat16 hh[8]; } u;
#pragma unroll
        for (int q = 0; q < 8; ++q)
          u.hh[q] = __float2bfloat16((xv[q] - st.x) * st.y * wv[q] + bv[q]);
        *(int4*)(dst + ((scol * 2 + t * 16) ^ sw)) = u.i4;
      }
    }
    {
      const char* bp = (const char*)Wt + ((size_t)(n0 + srow) * K + k0 + scol) * 2;
      char* dst = BsB + srow * 256;
      int sw = (srow & 7) << 4;
#pragma unroll
      for (int t = 0; t < 8; ++t) {
        int4 raw = *(const int4*)(bp + t * 16);
        *(int4*)(dst + ((scol * 2 + t * 16) ^ sw)) = raw;
      }
    }
    __syncthreads();
#pragma unroll
    for (int ks = 0; ks < 4; ++ks) {
      int kb = ks * 64 + lq * 16;
      bf16x8 af[4], bfr[4];
#pragma unroll
      for (int mi = 0; mi < 4; ++mi) {
        int r = wm * 64 + mi * 16 + lrow;
        af[mi] = *(const bf16x8*)(AsB + r * 256 + (kb ^ ((r & 7) << 4)));
      }
#pragma unroll
      for (int ni = 0; ni < 4; ++ni) {
        int r = wn * 64 + ni * 16 + lrow;
        bfr[ni] = *(const bf16x8*)(BsB + r * 256 + (kb ^ ((r & 7) << 4)));
      }
#pragma unroll
      for (int mi = 0; mi < 4; ++mi)
#pragma unroll
        for (int ni = 0; ni < 4; ++ni)
          acc[mi][ni] = __builtin_amdgcn_mfma_f32_16x16x32_bf16(af[mi], bfr[ni], acc[mi][ni], 0, 0, 0);
    }
    __syncthreads();
  }

  float bv[4];
#pragma unroll
  for (int ni = 0; ni < 4; ++ni) bv[ni] = bias[n0 + wn * 64 + ni * 16 + lrow];
#pragma unroll
  for (int mi = 0; mi < 4; ++mi) {
#pragma unroll
    for (int j = 0; j < 4; ++j) {
      int rowg = m0 + wm * 64 + mi * 16 + lq * 4 + j;
      int orow = (EPI == 2) ? wt_to_tok(rowg) : rowg;
#pragma unroll
      for (int ni = 0; ni < 4; ++ni) {
        int colg = n0 + wn * 64 + ni * 16 + lrow;
        float val = acc[mi][ni][j] + bv[ni];
        if (EPI == 0) {
          ((__hip_bfloat16*)outv)[(size_t)rowg * ldo + colg] = __float2bfloat16(val);
        } else if (EPI == 1) {
          float g = 0.5f * val * (1.0f + erff(val * 0.70710678118654752f));
          ((__hip_bfloat16*)outv)[(size_t)rowg * ldo + colg] = __float2bfloat16(g);
        } else {
          float r = res[(size_t)orow * 128 + colg];
          ((float*)outv)[(size_t)orow * 128 + colg] = val + r;
        }
      }
    }
  }
}

extern "C" void kernel_launch(void* const* d_in, const int* in_sizes, int n_in,
                              void* d_out, int out_size, void* d_ws, size_t ws_size,
                              hipStream_t stream) {
  (void)in_sizes; (void)n_in; (void)out_size; (void)ws_size;
  const float* x     = (const float*)d_in[0];
  const float* n1w   = (const float*)d_in[1];
  const float* n1b   = (const float*)d_in[2];
  const float* qkvw  = (const float*)d_in[3];
  const float* qkvb  = (const float*)d_in[4];
  const float* projw = (const float*)d_in[5];
  const float* projb = (const float*)d_in[6];
  const float* ptab  = (const float*)d_in[7];
  const float* w1    = (const float*)d_in[8];
  const float* b1    = (const float*)d_in[9];
  const float* w2    = (const float*)d_in[10];
  const float* b2    = (const float*)d_in[11];
  const float* n2w   = (const float*)d_in[12];
  const float* n2b   = (const float*)d_in[13];
  float* out = (float*)d_out;

  char* ws = (char*)d_ws;
  __hip_bfloat16* qkv = (__hip_bfloat16*)ws;
  __hip_bfloat16* u   = (__hip_bfloat16*)ws;
  float* x2  = (float*)(ws + 102760448);
  float* st1 = (float*)(ws + 154140672);
  float* st2 = (float*)(ws + 154943488);
  __hip_bfloat16* qkvwT = (__hip_bfloat16*)(ws + 155746304);             // [384][128]
  __hip_bfloat16* projwT = (__hip_bfloat16*)(ws + 155746304 + 98304);    // [128][128]
  __hip_bfloat16* w1T = (__hip_bfloat16*)(ws + 155746304 + 131072);      // [512][128]
  __hip_bfloat16* w2T = (__hip_bfloat16*)(ws + 155746304 + 262144);      // [128][512]

  prep_w<<<(384 * 128 + 255) / 256, 256, 0, stream>>>(qkvw, qkvwT, 128, 384);
  prep_w<<<(128 * 128 + 255) / 256, 256, 0, stream>>>(projw, projwT, 128, 128);
  prep_w<<<(512 * 128 + 255) / 256, 256, 0, stream>>>(w1, w1T, 128, 512);
  prep_w<<<(128 * 512 + 255) / 256, 256, 0, stream>>>(w2, w2T, 512, 128);

  ln_stats<<<NTOK / 4, 256, 0, stream>>>(x, st1);
  gemm_mfma<0, 0><<<dim3(784, 3), 256, 0, stream>>>(x, 128, qkvwT, qkvb,
                                                    qkv, 384, st1, n1w, n1b, nullptr, 128);
  attn_mfma<<<2048, 256, 0, stream>>>(qkv, ptab);
  gemm_mfma<2, 2><<<dim3(784, 1), 256, 0, stream>>>(qkv, 384, projwT, projb,
                                                    x2, 128, nullptr, nullptr, nullptr, x, 128);
  ln_stats<<<NTOK / 4, 256, 0, stream>>>(x2, st2);
  gemm_mfma<1, 1><<<dim3(784, 4), 256, 0, stream>>>(x2, 128, w1T, b1,
                                                    (void*)u, 512, st2, n2w, n2b, nullptr, 128);
  gemm_mfma<2, 3><<<dim3(784, 1), 256, 0, stream>>>(u, 512, w2T, b2,
                                                    out, 128, nullptr, nullptr, nullptr, x2, 512);
}

// Round 4
// 271.507 us; speedup vs baseline: 2.7910x; 1.1901x over previous
//
#include <hip/hip_runtime.h>
#include <hip/hip_bf16.h>

// Swin block: B=32, HW=56, C=128, WS=7, SS=3, NH=4, HD=32
#define NTOK 100352
#define SCALE_Q 0.17677669529663687f  // 32^-0.5

typedef __bf16 bf16x8 __attribute__((ext_vector_type(8)));
typedef float f32x4 __attribute__((ext_vector_type(4)));
struct bf2 { __hip_bfloat16 x, y; };

// window-token (wt = w*49+n) -> original flat token index in x
__device__ __forceinline__ int wt_to_tok(int wt) {
  int w = wt / 49, n = wt - w * 49;
  int b = w >> 6, wi = w & 63;
  int gh = wi >> 3, gw = wi & 7;
  int r = n / 7, c = n - r * 7;
  int hs = gh * 7 + r + 3; if (hs >= 56) hs -= 56;   // undo roll(-3)
  int ws = gw * 7 + c + 3; if (ws >= 56) ws -= 56;
  return (b * 56 + hs) * 56 + ws;
}

// all weight transposes + bf16 in one launch. dst segments:
// [0,49152) qkvwT[384][128]; [49152,65536) projwT[128][128];
// [65536,131072) w1T[512][128]; [131072,196608) w2T[128][512]
__global__ __launch_bounds__(256) void prep_all(const float* __restrict__ qkvw,
                                                const float* __restrict__ projw,
                                                const float* __restrict__ w1,
                                                const float* __restrict__ w2,
                                                __hip_bfloat16* __restrict__ dst) {
  int i = blockIdx.x * 256 + threadIdx.x;
  float v;
  if (i < 49152) { int n = i >> 7, k = i & 127; v = qkvw[k * 384 + n]; }
  else if (i < 65536) { int j = i - 49152; int n = j >> 7, k = j & 127; v = projw[k * 128 + n]; }
  else if (i < 131072) { int j = i - 65536; int n = j >> 7, k = j & 127; v = w1[k * 512 + n]; }
  else { int j = i - 131072; int n = j / 512, k = j - n * 512; v = w2[k * 128 + n]; }
  dst[i] = __float2bfloat16(v);
}

// xn[wt] = bf16(LN1(x[tok])) — gather to window order fused
__global__ __launch_bounds__(256) void ln1_apply(const float* __restrict__ x,
                                                 const float* __restrict__ nw,
                                                 const float* __restrict__ nb,
                                                 __hip_bfloat16* __restrict__ xn) {
  int wt = blockIdx.x * 4 + (threadIdx.x >> 6);
  int lane = threadIdx.x & 63;
  int tok = wt_to_tok(wt);
  float2 v = *(const float2*)(x + (size_t)tok * 128 + lane * 2);
  float s = v.x + v.y, ss = v.x * v.x + v.y * v.y;
#pragma unroll
  for (int off = 32; off; off >>= 1) {
    s += __shfl_xor(s, off);
    ss += __shfl_xor(ss, off);
  }
  float mu = s * (1.0f / 128.0f);
  float rstd = rsqrtf(ss * (1.0f / 128.0f) - mu * mu + 1e-5f);
  float2 wv = *(const float2*)(nw + lane * 2);
  float2 bv = *(const float2*)(nb + lane * 2);
  bf2 o;
  o.x = __float2bfloat16((v.x - mu) * rstd * wv.x + bv.x);
  o.y = __float2bfloat16((v.y - mu) * rstd * wv.y + bv.y);
  *(bf2*)(xn + (size_t)wt * 128 + lane * 2) = o;
}

// ---------------------------------------------------------------------------
// MFMA attention: 1 block = 1 window, wave h = head h. 49 tokens padded to 64.
// qkv bf16 [wt][384]; output -> compact attnout [wt][128].
// ---------------------------------------------------------------------------
__global__ __launch_bounds__(256) void attn_mfma(const __hip_bfloat16* __restrict__ qkv,
                                                 const float* __restrict__ ptab,
                                                 __hip_bfloat16* __restrict__ attnout) {
  __shared__ __align__(16) char lds[4 * 12288];
  const int tid = threadIdx.x;
  const int lane = tid & 63, h = tid >> 6;
  const int w = blockIdx.x;
  const int wi = w & 63, gh = wi >> 3, gw = wi & 7;
  char* Pl = lds + h * 12288;
  char* VTl = Pl + 8192;
  const int lxi = lane & 15, lq = lane >> 4, lg4 = (lane >> 4) * 4;

  const __hip_bfloat16* base = qkv + (size_t)w * 49 * 384 + h * 32;
  __hip_bfloat16* op = attnout + (size_t)w * 49 * 128 + h * 32;

  bf16x8 qa[4], kb[4];
#pragma unroll
  for (int mi = 0; mi < 4; ++mi) {
    int t = mi * 16 + lxi; if (t > 48) t = 48;
    qa[mi] = *(const bf16x8*)(base + (size_t)t * 384 + lq * 8);
    kb[mi] = *(const bf16x8*)(base + (size_t)t * 384 + 128 + lq * 8);
  }
  {
    union { bf16x8 v; __hip_bfloat16 e[8]; } vv[4];
    const __hip_bfloat16* vp = base + (size_t)(lane < 49 ? lane : 0) * 384 + 256;
#pragma unroll
    for (int q = 0; q < 4; ++q) vv[q].v = *(const bf16x8*)(vp + q * 8);
    __hip_bfloat16 z = __float2bfloat16(0.0f);
#pragma unroll
    for (int q = 0; q < 4; ++q)
#pragma unroll
      for (int e = 0; e < 8; ++e) {
        int d = q * 8 + e;
        __hip_bfloat16 val = (lane < 49) ? vv[q].e[e] : z;
        *(__hip_bfloat16*)(VTl + d * 128 + ((lane * 2) ^ ((d & 7) << 4))) = val;
      }
  }

  f32x4 s[4][4] = {};
#pragma unroll
  for (int mi = 0; mi < 4; ++mi)
#pragma unroll
    for (int ni = 0; ni < 4; ++ni)
      s[mi][ni] = __builtin_amdgcn_mfma_f32_16x16x32_bf16(qa[mi], kb[ni], s[mi][ni], 0, 0, 0);

  int rj[4], cj[4], cntj[4], jbad[4];
#pragma unroll
  for (int ni = 0; ni < 4; ++ni) {
    int jc = ni * 16 + lxi;
    jbad[ni] = (jc > 48);
    int jj = jbad[ni] ? 48 : jc;
    rj[ni] = jj / 7; cj[ni] = jj - rj[ni] * 7;
    int hj = gh * 7 + rj[ni], wj = gw * 7 + cj[ni];
    cntj[ni] = (hj < 49 ? 0 : (hj < 53 ? 3 : 6)) + (wj < 49 ? 0 : (wj < 53 ? 1 : 2));
  }
#pragma unroll
  for (int mi = 0; mi < 4; ++mi)
#pragma unroll
    for (int j = 0; j < 4; ++j) {
      int i = mi * 16 + lg4 + j; if (i > 48) i = 48;
      int ri = i / 7, ci = i - ri * 7;
      int hi_ = gh * 7 + ri, wi_ = gw * 7 + ci;
      int cnti = (hi_ < 49 ? 0 : (hi_ < 53 ? 3 : 6)) + (wi_ < 49 ? 0 : (wi_ < 53 ? 1 : 2));
#pragma unroll
      for (int ni = 0; ni < 4; ++ni) {
        float b = ptab[((ri - rj[ni] + 6) * 13 + (ci - cj[ni] + 6)) * 4 + h];
        float val = s[mi][ni][j] * SCALE_Q + b;
        if (cnti != cntj[ni]) val -= 100.0f;
        if (jbad[ni]) val = -1e30f;
        s[mi][ni][j] = val;
      }
    }

#pragma unroll
  for (int mi = 0; mi < 4; ++mi)
#pragma unroll
    for (int j = 0; j < 4; ++j) {
      float m = fmaxf(fmaxf(s[mi][0][j], s[mi][1][j]), fmaxf(s[mi][2][j], s[mi][3][j]));
#pragma unroll
      for (int off = 8; off; off >>= 1) m = fmaxf(m, __shfl_xor(m, off));
      float e[4], sum = 0.0f;
#pragma unroll
      for (int ni = 0; ni < 4; ++ni) { e[ni] = __expf(s[mi][ni][j] - m); sum += e[ni]; }
#pragma unroll
      for (int off = 8; off; off >>= 1) sum += __shfl_xor(sum, off);
      float inv = 1.0f / sum;
#pragma unroll
      for (int ni = 0; ni < 4; ++ni) s[mi][ni][j] = e[ni] * inv;
    }

#pragma unroll
  for (int mi = 0; mi < 4; ++mi)
#pragma unroll
    for (int j = 0; j < 4; ++j) {
      int row = mi * 16 + lg4 + j;
      int sw = (row & 7) << 4;
      char* prow = Pl + row * 128;
#pragma unroll
      for (int ni = 0; ni < 4; ++ni)
        *(__hip_bfloat16*)(prow + (((ni * 16 + lxi) * 2) ^ sw)) =
            __float2bfloat16(s[mi][ni][j]);
    }

  __syncthreads();

  f32x4 o[4][2] = {};
#pragma unroll
  for (int ks = 0; ks < 2; ++ks) {
    bf16x8 pa[4], vb[2];
#pragma unroll
    for (int mi = 0; mi < 4; ++mi) {
      int row = mi * 16 + lxi;
      pa[mi] = *(const bf16x8*)(Pl + row * 128 + ((ks * 64 + lq * 16) ^ ((row & 7) << 4)));
    }
#pragma unroll
    for (int ni = 0; ni < 2; ++ni) {
      int row = ni * 16 + lxi;
      vb[ni] = *(const bf16x8*)(VTl + row * 128 + ((ks * 64 + lq * 16) ^ ((row & 7) << 4)));
    }
#pragma unroll
    for (int mi = 0; mi < 4; ++mi)
#pragma unroll
      for (int ni = 0; ni < 2; ++ni)
        o[mi][ni] = __builtin_amdgcn_mfma_f32_16x16x32_bf16(pa[mi], vb[ni], o[mi][ni], 0, 0, 0);
  }

#pragma unroll
  for (int mi = 0; mi < 4; ++mi)
#pragma unroll
    for (int j = 0; j < 4; ++j) {
      int q = mi * 16 + lg4 + j;
      if (q < 49) {
#pragma unroll
        for (int ni = 0; ni < 2; ++ni)
          op[(size_t)q * 128 + ni * 16 + lxi] = __float2bfloat16(o[mi][ni][j]);
      }
    }
}

// ---------------------------------------------------------------------------
// MFMA bf16 GEMM: 128x128 tile, BK=128, 256 threads (4 waves, 2x2 of 64x64).
// A: bf16 [M][lda]; B^T: [N][K] bf16.
// EPI: 0 = +bias -> bf16 (ldo)
//      1 = gelu(+bias) -> bf16 (ldo)
//      3 = +bias +res[m] -> fp32 out[m] (stride 128)
//      4 = proj+LN2 fused: rows are wt; tok=wt_to_tok(row);
//          x2[tok]=acc+bias+res[tok] (fp32); out2[tok]=bf16(LN(x2 row)*nw+nb)
// ---------------------------------------------------------------------------
template<int EPI>
__global__ __launch_bounds__(256) void gemm_mfma(
    const __hip_bfloat16* __restrict__ A, int lda,
    const __hip_bfloat16* __restrict__ Wt,
    const float* __restrict__ bias,
    void* __restrict__ outv, int ldo,
    __hip_bfloat16* __restrict__ out2,
    const float* __restrict__ nw, const float* __restrict__ nb,
    const float* __restrict__ res, int K)
{
  __shared__ __align__(16) char AsB[128 * 256];
  __shared__ __align__(16) char BsB[128 * 256];
  const int tid = threadIdx.x;
  const int m0 = blockIdx.x * 128, n0 = blockIdx.y * 128;
  const int srow = tid >> 1;
  const int scol = (tid & 1) * 64;
  const int lane = tid & 63, wid = tid >> 6;
  const int wm = wid >> 1, wn = wid & 1;
  const int lrow = lane & 15, lq = lane >> 4;

  f32x4 acc[4][4] = {};

  for (int k0 = 0; k0 < K; k0 += 128) {
    {
      const char* ap = (const char*)A + ((size_t)(m0 + srow) * lda + k0 + scol) * 2;
      char* dst = AsB + srow * 256;
      int sw = (srow & 7) << 4;
#pragma unroll
      for (int t = 0; t < 8; ++t) {
        int4 raw = *(const int4*)(ap + t * 16);
        *(int4*)(dst + ((scol * 2 + t * 16) ^ sw)) = raw;
      }
    }
    {
      const char* bp = (const char*)Wt + ((size_t)(n0 + srow) * K + k0 + scol) * 2;
      char* dst = BsB + srow * 256;
      int sw = (srow & 7) << 4;
#pragma unroll
      for (int t = 0; t < 8; ++t) {
        int4 raw = *(const int4*)(bp + t * 16);
        *(int4*)(dst + ((scol * 2 + t * 16) ^ sw)) = raw;
      }
    }
    __syncthreads();
#pragma unroll
    for (int ks = 0; ks < 4; ++ks) {
      int kb = ks * 64 + lq * 16;
      bf16x8 af[4], bfr[4];
#pragma unroll
      for (int mi = 0; mi < 4; ++mi) {
        int r = wm * 64 + mi * 16 + lrow;
        af[mi] = *(const bf16x8*)(AsB + r * 256 + (kb ^ ((r & 7) << 4)));
      }
#pragma unroll
      for (int ni = 0; ni < 4; ++ni) {
        int r = wn * 64 + ni * 16 + lrow;
        bfr[ni] = *(const bf16x8*)(BsB + r * 256 + (kb ^ ((r & 7) << 4)));
      }
#pragma unroll
      for (int mi = 0; mi < 4; ++mi)
#pragma unroll
        for (int ni = 0; ni < 4; ++ni)
          acc[mi][ni] = __builtin_amdgcn_mfma_f32_16x16x32_bf16(af[mi], bfr[ni], acc[mi][ni], 0, 0, 0);
    }
    __syncthreads();
  }

  float bv[4];
#pragma unroll
  for (int ni = 0; ni < 4; ++ni) bv[ni] = bias[n0 + wn * 64 + ni * 16 + lrow];

  if (EPI == 4) {
    // proj + residual + LN2 fused. n0 == 0, grid.y == 1: block owns full rows.
    float* x2 = (float*)outv;
    float* redS = (float*)AsB;          // [128][2]
    float* redQ = (float*)(AsB + 1024); // [128][2]
    float nwc[4], nbc[4];
#pragma unroll
    for (int ni = 0; ni < 4; ++ni) {
      int colg = wn * 64 + ni * 16 + lrow;
      nwc[ni] = nw[colg]; nbc[ni] = nb[colg];
    }
    int toks[4][4];
#pragma unroll
    for (int mi = 0; mi < 4; ++mi)
#pragma unroll
      for (int j = 0; j < 4; ++j) {
        int row = wm * 64 + mi * 16 + lq * 4 + j;
        int tok = wt_to_tok(m0 + row);
        toks[mi][j] = tok;
        float s = 0.0f, ss = 0.0f;
#pragma unroll
        for (int ni = 0; ni < 4; ++ni) {
          int colg = wn * 64 + ni * 16 + lrow;
          float val = acc[mi][ni][j] + bv[ni] + res[(size_t)tok * 128 + colg];
          x2[(size_t)tok * 128 + colg] = val;
          acc[mi][ni][j] = val;
          s += val; ss += val * val;
        }
#pragma unroll
        for (int off = 8; off; off >>= 1) {
          s += __shfl_xor(s, off);
          ss += __shfl_xor(ss, off);
        }
        if (lrow == 0) { redS[row * 2 + wn] = s; redQ[row * 2 + wn] = ss; }
      }
    __syncthreads();
#pragma unroll
    for (int mi = 0; mi < 4; ++mi)
#pragma unroll
      for (int j = 0; j < 4; ++j) {
        int row = wm * 64 + mi * 16 + lq * 4 + j;
        float s = redS[row * 2] + redS[row * 2 + 1];
        float ss = redQ[row * 2] + redQ[row * 2 + 1];
        float mu = s * (1.0f / 128.0f);
        float rstd = rsqrtf(ss * (1.0f / 128.0f) - mu * mu + 1e-5f);
        int tok = toks[mi][j];
#pragma unroll
        for (int ni = 0; ni < 4; ++ni) {
          int colg = wn * 64 + ni * 16 + lrow;
          float xnv = (acc[mi][ni][j] - mu) * rstd * nwc[ni] + nbc[ni];
          out2[(size_t)tok * 128 + colg] = __float2bfloat16(xnv);
        }
      }
    return;
  }

#pragma unroll
  for (int mi = 0; mi < 4; ++mi) {
#pragma unroll
    for (int j = 0; j < 4; ++j) {
      int rowg = m0 + wm * 64 + mi * 16 + lq * 4 + j;
#pragma unroll
      for (int ni = 0; ni < 4; ++ni) {
        int colg = n0 + wn * 64 + ni * 16 + lrow;
        float val = acc[mi][ni][j] + bv[ni];
        if (EPI == 0) {
          ((__hip_bfloat16*)outv)[(size_t)rowg * ldo + colg] = __float2bfloat16(val);
        } else if (EPI == 1) {
          float g = 0.5f * val * (1.0f + erff(val * 0.70710678118654752f));
          ((__hip_bfloat16*)outv)[(size_t)rowg * ldo + colg] = __float2bfloat16(g);
        } else {
          float r = res[(size_t)rowg * 128 + colg];
          ((float*)outv)[(size_t)rowg * 128 + colg] = val + r;
        }
      }
    }
  }
}

extern "C" void kernel_launch(void* const* d_in, const int* in_sizes, int n_in,
                              void* d_out, int out_size, void* d_ws, size_t ws_size,
                              hipStream_t stream) {
  (void)in_sizes; (void)n_in; (void)out_size; (void)ws_size;
  const float* x     = (const float*)d_in[0];
  const float* n1w   = (const float*)d_in[1];
  const float* n1b   = (const float*)d_in[2];
  const float* qkvw  = (const float*)d_in[3];
  const float* qkvb  = (const float*)d_in[4];
  const float* projw = (const float*)d_in[5];
  const float* projb = (const float*)d_in[6];
  const float* ptab  = (const float*)d_in[7];
  const float* w1    = (const float*)d_in[8];
  const float* b1    = (const float*)d_in[9];
  const float* w2    = (const float*)d_in[10];
  const float* b2    = (const float*)d_in[11];
  const float* n2w   = (const float*)d_in[12];
  const float* n2b   = (const float*)d_in[13];
  float* out = (float*)d_out;

  // workspace layout (bytes):
  //   [0,          25690112)   xn   bf16 [wt][128]  (LN1, window order)
  //   [25690112,  102760448)   qkv  bf16 [wt][384]
  //   [102760448, 128450560)   attnout bf16 [wt][128]
  //     u bf16 [tok][512] aliases [25690112, 128450560)  (qkv+attnout dead)
  //   [128450560, 179830784)   x2   fp32 [tok][128]
  //   [179830784, 205520896)   x2n  bf16 [tok][128]  (LN2 applied)
  //   [205520896, 205914112)   transposed bf16 weights
  char* ws = (char*)d_ws;
  __hip_bfloat16* xn      = (__hip_bfloat16*)ws;
  __hip_bfloat16* qkv     = (__hip_bfloat16*)(ws + 25690112);
  __hip_bfloat16* attnout = (__hip_bfloat16*)(ws + 102760448);
  __hip_bfloat16* u       = (__hip_bfloat16*)(ws + 25690112);
  float* x2               = (float*)(ws + 128450560);
  __hip_bfloat16* x2n     = (__hip_bfloat16*)(ws + 179830784);
  __hip_bfloat16* wbase   = (__hip_bfloat16*)(ws + 205520896);
  __hip_bfloat16* qkvwT  = wbase;            // [384][128]
  __hip_bfloat16* projwT = wbase + 49152;    // [128][128]
  __hip_bfloat16* w1T    = wbase + 65536;    // [512][128]
  __hip_bfloat16* w2T    = wbase + 131072;   // [128][512]

  prep_all<<<768, 256, 0, stream>>>(qkvw, projw, w1, w2, wbase);
  ln1_apply<<<NTOK / 4, 256, 0, stream>>>(x, n1w, n1b, xn);
  // qkv = xn @ qkv_w + qkv_b  (bf16)
  gemm_mfma<0><<<dim3(784, 3), 256, 0, stream>>>(xn, 128, qkvwT, qkvb,
                                                 qkv, 384, nullptr, nullptr, nullptr, nullptr, 128);
  attn_mfma<<<2048, 256, 0, stream>>>(qkv, ptab, attnout);
  // x2[tok] = x[tok] + attnout @ proj_w + proj_b ; x2n = bf16(LN2(x2))
  gemm_mfma<4><<<dim3(784, 1), 256, 0, stream>>>(attnout, 128, projwT, projb,
                                                 x2, 128, x2n, n2w, n2b, x, 128);
  // u = gelu(x2n @ w1 + b1)
  gemm_mfma<1><<<dim3(784, 4), 256, 0, stream>>>(x2n, 128, w1T, b1,
                                                 (void*)u, 512, nullptr, nullptr, nullptr, nullptr, 128);
  // out = x2 + u @ w2 + b2
  gemm_mfma<3><<<dim3(784, 1), 256, 0, stream>>>(u, 512, w2T, b2,
                                                 out, 128, nullptr, nullptr, nullptr, x2, 512);
}

// Round 5
// 256.683 us; speedup vs baseline: 2.9522x; 1.0578x over previous
//
#include <hip/hip_runtime.h>
#include <hip/hip_bf16.h>

// Swin block: B=32, HW=56, C=128, WS=7, SS=3, NH=4, HD=32
#define NTOK 100352
#define SCALE_Q 0.17677669529663687f  // 32^-0.5

typedef __bf16 bf16x8 __attribute__((ext_vector_type(8)));
typedef float f32x4 __attribute__((ext_vector_type(4)));
struct bf2 { __hip_bfloat16 x, y; };

// window-token (wt = w*49+n) -> original flat token index in x
__device__ __forceinline__ int wt_to_tok(int wt) {
  int w = wt / 49, n = wt - w * 49;
  int b = w >> 6, wi = w & 63;
  int gh = wi >> 3, gw = wi & 7;
  int r = n / 7, c = n - r * 7;
  int hs = gh * 7 + r + 3; if (hs >= 56) hs -= 56;   // undo roll(-3)
  int ws = gw * 7 + c + 3; if (ws >= 56) ws -= 56;
  return (b * 56 + hs) * 56 + ws;
}

// tanh-approx GELU (overflow-safe), ~10 VALU ops vs ~30+ for erff
__device__ __forceinline__ float gelu_fast(float v) {
  float y = 0.7978845608028654f * (v + 0.044715f * v * v * v);
  float ay = fabsf(y);
  float e = __expf(-2.0f * ay);
  float t = (1.0f - e) / (1.0f + e);          // tanh(|y|)
  t = copysignf(t, y);
  return 0.5f * v * (1.0f + t);
}

// all weight transposes + bf16 in one launch
__global__ __launch_bounds__(256) void prep_all(const float* __restrict__ qkvw,
                                                const float* __restrict__ projw,
                                                const float* __restrict__ w1,
                                                const float* __restrict__ w2,
                                                __hip_bfloat16* __restrict__ dst) {
  int i = blockIdx.x * 256 + threadIdx.x;
  float v;
  if (i < 49152) { int n = i >> 7, k = i & 127; v = qkvw[k * 384 + n]; }
  else if (i < 65536) { int j = i - 49152; int n = j >> 7, k = j & 127; v = projw[k * 128 + n]; }
  else if (i < 131072) { int j = i - 65536; int n = j >> 7, k = j & 127; v = w1[k * 512 + n]; }
  else { int j = i - 131072; int n = j / 512, k = j - n * 512; v = w2[k * 128 + n]; }
  dst[i] = __float2bfloat16(v);
}

// xn[wt] = bf16(LN1(x[tok])) — gather to window order fused
__global__ __launch_bounds__(256) void ln1_apply(const float* __restrict__ x,
                                                 const float* __restrict__ nw,
                                                 const float* __restrict__ nb,
                                                 __hip_bfloat16* __restrict__ xn) {
  int wt = blockIdx.x * 4 + (threadIdx.x >> 6);
  int lane = threadIdx.x & 63;
  int tok = wt_to_tok(wt);
  float2 v = *(const float2*)(x + (size_t)tok * 128 + lane * 2);
  float s = v.x + v.y, ss = v.x * v.x + v.y * v.y;
#pragma unroll
  for (int off = 32; off; off >>= 1) {
    s += __shfl_xor(s, off);
    ss += __shfl_xor(ss, off);
  }
  float mu = s * (1.0f / 128.0f);
  float rstd = rsqrtf(ss * (1.0f / 128.0f) - mu * mu + 1e-5f);
  float2 wv = *(const float2*)(nw + lane * 2);
  float2 bv = *(const float2*)(nb + lane * 2);
  bf2 o;
  o.x = __float2bfloat16((v.x - mu) * rstd * wv.x + bv.x);
  o.y = __float2bfloat16((v.y - mu) * rstd * wv.y + bv.y);
  *(bf2*)(xn + (size_t)wt * 128 + lane * 2) = o;
}

// ---------------------------------------------------------------------------
// MFMA attention (unchanged from round 3): 1 block = 1 window, wave h = head h.
// ---------------------------------------------------------------------------
__global__ __launch_bounds__(256) void attn_mfma(const __hip_bfloat16* __restrict__ qkv,
                                                 const float* __restrict__ ptab,
                                                 __hip_bfloat16* __restrict__ attnout) {
  __shared__ __align__(16) char lds[4 * 12288];
  const int tid = threadIdx.x;
  const int lane = tid & 63, h = tid >> 6;
  const int w = blockIdx.x;
  const int wi = w & 63, gh = wi >> 3, gw = wi & 7;
  char* Pl = lds + h * 12288;
  char* VTl = Pl + 8192;
  const int lxi = lane & 15, lq = lane >> 4, lg4 = (lane >> 4) * 4;

  const __hip_bfloat16* base = qkv + (size_t)w * 49 * 384 + h * 32;
  __hip_bfloat16* op = attnout + (size_t)w * 49 * 128 + h * 32;

  bf16x8 qa[4], kb[4];
#pragma unroll
  for (int mi = 0; mi < 4; ++mi) {
    int t = mi * 16 + lxi; if (t > 48) t = 48;
    qa[mi] = *(const bf16x8*)(base + (size_t)t * 384 + lq * 8);
    kb[mi] = *(const bf16x8*)(base + (size_t)t * 384 + 128 + lq * 8);
  }
  {
    union { bf16x8 v; __hip_bfloat16 e[8]; } vv[4];
    const __hip_bfloat16* vp = base + (size_t)(lane < 49 ? lane : 0) * 384 + 256;
#pragma unroll
    for (int q = 0; q < 4; ++q) vv[q].v = *(const bf16x8*)(vp + q * 8);
    __hip_bfloat16 z = __float2bfloat16(0.0f);
#pragma unroll
    for (int q = 0; q < 4; ++q)
#pragma unroll
      for (int e = 0; e < 8; ++e) {
        int d = q * 8 + e;
        __hip_bfloat16 val = (lane < 49) ? vv[q].e[e] : z;
        *(__hip_bfloat16*)(VTl + d * 128 + ((lane * 2) ^ ((d & 7) << 4))) = val;
      }
  }

  f32x4 s[4][4] = {};
#pragma unroll
  for (int mi = 0; mi < 4; ++mi)
#pragma unroll
    for (int ni = 0; ni < 4; ++ni)
      s[mi][ni] = __builtin_amdgcn_mfma_f32_16x16x32_bf16(qa[mi], kb[ni], s[mi][ni], 0, 0, 0);

  int rj[4], cj[4], cntj[4], jbad[4];
#pragma unroll
  for (int ni = 0; ni < 4; ++ni) {
    int jc = ni * 16 + lxi;
    jbad[ni] = (jc > 48);
    int jj = jbad[ni] ? 48 : jc;
    rj[ni] = jj / 7; cj[ni] = jj - rj[ni] * 7;
    int hj = gh * 7 + rj[ni], wj = gw * 7 + cj[ni];
    cntj[ni] = (hj < 49 ? 0 : (hj < 53 ? 3 : 6)) + (wj < 49 ? 0 : (wj < 53 ? 1 : 2));
  }
#pragma unroll
  for (int mi = 0; mi < 4; ++mi)
#pragma unroll
    for (int j = 0; j < 4; ++j) {
      int i = mi * 16 + lg4 + j; if (i > 48) i = 48;
      int ri = i / 7, ci = i - ri * 7;
      int hi_ = gh * 7 + ri, wi_ = gw * 7 + ci;
      int cnti = (hi_ < 49 ? 0 : (hi_ < 53 ? 3 : 6)) + (wi_ < 49 ? 0 : (wi_ < 53 ? 1 : 2));
#pragma unroll
      for (int ni = 0; ni < 4; ++ni) {
        float b = ptab[((ri - rj[ni] + 6) * 13 + (ci - cj[ni] + 6)) * 4 + h];
        float val = s[mi][ni][j] * SCALE_Q + b;
        if (cnti != cntj[ni]) val -= 100.0f;
        if (jbad[ni]) val = -1e30f;
        s[mi][ni][j] = val;
      }
    }

#pragma unroll
  for (int mi = 0; mi < 4; ++mi)
#pragma unroll
    for (int j = 0; j < 4; ++j) {
      float m = fmaxf(fmaxf(s[mi][0][j], s[mi][1][j]), fmaxf(s[mi][2][j], s[mi][3][j]));
#pragma unroll
      for (int off = 8; off; off >>= 1) m = fmaxf(m, __shfl_xor(m, off));
      float e[4], sum = 0.0f;
#pragma unroll
      for (int ni = 0; ni < 4; ++ni) { e[ni] = __expf(s[mi][ni][j] - m); sum += e[ni]; }
#pragma unroll
      for (int off = 8; off; off >>= 1) sum += __shfl_xor(sum, off);
      float inv = 1.0f / sum;
#pragma unroll
      for (int ni = 0; ni < 4; ++ni) s[mi][ni][j] = e[ni] * inv;
    }

#pragma unroll
  for (int mi = 0; mi < 4; ++mi)
#pragma unroll
    for (int j = 0; j < 4; ++j) {
      int row = mi * 16 + lg4 + j;
      int sw = (row & 7) << 4;
      char* prow = Pl + row * 128;
#pragma unroll
      for (int ni = 0; ni < 4; ++ni)
        *(__hip_bfloat16*)(prow + (((ni * 16 + lxi) * 2) ^ sw)) =
            __float2bfloat16(s[mi][ni][j]);
    }

  __syncthreads();

  f32x4 o[4][2] = {};
#pragma unroll
  for (int ks = 0; ks < 2; ++ks) {
    bf16x8 pa[4], vb[2];
#pragma unroll
    for (int mi = 0; mi < 4; ++mi) {
      int row = mi * 16 + lxi;
      pa[mi] = *(const bf16x8*)(Pl + row * 128 + ((ks * 64 + lq * 16) ^ ((row & 7) << 4)));
    }
#pragma unroll
    for (int ni = 0; ni < 2; ++ni) {
      int row = ni * 16 + lxi;
      vb[ni] = *(const bf16x8*)(VTl + row * 128 + ((ks * 64 + lq * 16) ^ ((row & 7) << 4)));
    }
#pragma unroll
    for (int mi = 0; mi < 4; ++mi)
#pragma unroll
      for (int ni = 0; ni < 2; ++ni)
        o[mi][ni] = __builtin_amdgcn_mfma_f32_16x16x32_bf16(pa[mi], vb[ni], o[mi][ni], 0, 0, 0);
  }

#pragma unroll
  for (int mi = 0; mi < 4; ++mi)
#pragma unroll
    for (int j = 0; j < 4; ++j) {
      int q = mi * 16 + lg4 + j;
      if (q < 49) {
#pragma unroll
        for (int ni = 0; ni < 2; ++ni)
          op[(size_t)q * 128 + ni * 16 + lxi] = __float2bfloat16(o[mi][ni][j]);
      }
    }
}

// ---------------------------------------------------------------------------
// MFMA bf16 GEMM: 128x128 tile, BK=128, 256 threads (4 waves, 2x2 of 64x64).
// 1D grid with XCD-grouped decode: all NB column-blocks of one row-panel land
// on the same XCD (bid%8), so A re-reads hit that XCD's L2.
// EPI: 0 = +bias -> bf16 (ldo)
//      1 = gelu_fast(+bias) -> bf16 (ldo)
//      3 = +bias +resb[m](bf16) -> fp32 out[m] (stride 128)
//      4 = proj+LN2 fused: rows are wt; tok=wt_to_tok(row);
//          x2[tok]=bf16(acc+bias+resf[tok]); out2[tok]=bf16(LN(row)*nw+nb)
// ---------------------------------------------------------------------------
template<int EPI>
__global__ __launch_bounds__(256) void gemm_mfma(
    const __hip_bfloat16* __restrict__ A, int lda, int NB,
    const __hip_bfloat16* __restrict__ Wt,
    const float* __restrict__ bias,
    void* __restrict__ outv, int ldo,
    __hip_bfloat16* __restrict__ out2,
    const float* __restrict__ nw, const float* __restrict__ nb,
    const float* __restrict__ resf, const __hip_bfloat16* __restrict__ resb,
    int K)
{
  __shared__ __align__(16) char AsB[128 * 256];
  __shared__ __align__(16) char BsB[128 * 256];
  const int bid = blockIdx.x;
  const int xcd = bid & 7, tt = bid >> 3;
  const int nbk = tt % NB, mseq = tt / NB;
  const int m0 = (mseq * 8 + xcd) * 128, n0 = nbk * 128;
  const int tid = threadIdx.x;
  const int srow = tid >> 1;
  const int scol = (tid & 1) * 64;
  const int lane = tid & 63, wid = tid >> 6;
  const int wm = wid >> 1, wn = wid & 1;
  const int lrow = lane & 15, lq = lane >> 4;

  f32x4 acc[4][4] = {};

  for (int k0 = 0; k0 < K; k0 += 128) {
    {
      const char* ap = (const char*)A + ((size_t)(m0 + srow) * lda + k0 + scol) * 2;
      char* dst = AsB + srow * 256;
      int sw = (srow & 7) << 4;
#pragma unroll
      for (int t = 0; t < 8; ++t) {
        int4 raw = *(const int4*)(ap + t * 16);
        *(int4*)(dst + ((scol * 2 + t * 16) ^ sw)) = raw;
      }
    }
    {
      const char* bp = (const char*)Wt + ((size_t)(n0 + srow) * K + k0 + scol) * 2;
      char* dst = BsB + srow * 256;
      int sw = (srow & 7) << 4;
#pragma unroll
      for (int t = 0; t < 8; ++t) {
        int4 raw = *(const int4*)(bp + t * 16);
        *(int4*)(dst + ((scol * 2 + t * 16) ^ sw)) = raw;
      }
    }
    __syncthreads();
#pragma unroll
    for (int ks = 0; ks < 4; ++ks) {
      int kb = ks * 64 + lq * 16;
      bf16x8 af[4], bfr[4];
#pragma unroll
      for (int mi = 0; mi < 4; ++mi) {
        int r = wm * 64 + mi * 16 + lrow;
        af[mi] = *(const bf16x8*)(AsB + r * 256 + (kb ^ ((r & 7) << 4)));
      }
#pragma unroll
      for (int ni = 0; ni < 4; ++ni) {
        int r = wn * 64 + ni * 16 + lrow;
        bfr[ni] = *(const bf16x8*)(BsB + r * 256 + (kb ^ ((r & 7) << 4)));
      }
#pragma unroll
      for (int mi = 0; mi < 4; ++mi)
#pragma unroll
        for (int ni = 0; ni < 4; ++ni)
          acc[mi][ni] = __builtin_amdgcn_mfma_f32_16x16x32_bf16(af[mi], bfr[ni], acc[mi][ni], 0, 0, 0);
    }
    __syncthreads();
  }

  float bv[4];
#pragma unroll
  for (int ni = 0; ni < 4; ++ni) bv[ni] = bias[n0 + wn * 64 + ni * 16 + lrow];

  if (EPI == 4) {
    // proj + residual + LN2 fused. NB == 1: block owns full 128-wide rows.
    __hip_bfloat16* x2 = (__hip_bfloat16*)outv;
    float* redS = (float*)AsB;          // [128][2]
    float* redQ = (float*)(AsB + 1024); // [128][2]
    float nwc[4], nbc[4];
#pragma unroll
    for (int ni = 0; ni < 4; ++ni) {
      int colg = wn * 64 + ni * 16 + lrow;
      nwc[ni] = nw[colg]; nbc[ni] = nb[colg];
    }
    int toks[4][4];
#pragma unroll
    for (int mi = 0; mi < 4; ++mi)
#pragma unroll
      for (int j = 0; j < 4; ++j) {
        int row = wm * 64 + mi * 16 + lq * 4 + j;
        int tok = wt_to_tok(m0 + row);
        toks[mi][j] = tok;
        float s = 0.0f, ss = 0.0f;
#pragma unroll
        for (int ni = 0; ni < 4; ++ni) {
          int colg = wn * 64 + ni * 16 + lrow;
          float val = acc[mi][ni][j] + bv[ni] + resf[(size_t)tok * 128 + colg];
          x2[(size_t)tok * 128 + colg] = __float2bfloat16(val);
          acc[mi][ni][j] = val;
          s += val; ss += val * val;
        }
#pragma unroll
        for (int off = 8; off; off >>= 1) {
          s += __shfl_xor(s, off);
          ss += __shfl_xor(ss, off);
        }
        if (lrow == 0) { redS[row * 2 + wn] = s; redQ[row * 2 + wn] = ss; }
      }
    __syncthreads();
#pragma unroll
    for (int mi = 0; mi < 4; ++mi)
#pragma unroll
      for (int j = 0; j < 4; ++j) {
        int row = wm * 64 + mi * 16 + lq * 4 + j;
        float s = redS[row * 2] + redS[row * 2 + 1];
        float ss = redQ[row * 2] + redQ[row * 2 + 1];
        float mu = s * (1.0f / 128.0f);
        float rstd = rsqrtf(ss * (1.0f / 128.0f) - mu * mu + 1e-5f);
        int tok = toks[mi][j];
#pragma unroll
        for (int ni = 0; ni < 4; ++ni) {
          int colg = wn * 64 + ni * 16 + lrow;
          float xnv = (acc[mi][ni][j] - mu) * rstd * nwc[ni] + nbc[ni];
          out2[(size_t)tok * 128 + colg] = __float2bfloat16(xnv);
        }
      }
    return;
  }

#pragma unroll
  for (int mi = 0; mi < 4; ++mi) {
#pragma unroll
    for (int j = 0; j < 4; ++j) {
      int rowg = m0 + wm * 64 + mi * 16 + lq * 4 + j;
#pragma unroll
      for (int ni = 0; ni < 4; ++ni) {
        int colg = n0 + wn * 64 + ni * 16 + lrow;
        float val = acc[mi][ni][j] + bv[ni];
        if (EPI == 0) {
          ((__hip_bfloat16*)outv)[(size_t)rowg * ldo + colg] = __float2bfloat16(val);
        } else if (EPI == 1) {
          ((__hip_bfloat16*)outv)[(size_t)rowg * ldo + colg] = __float2bfloat16(gelu_fast(val));
        } else {
          float r = __bfloat162float(resb[(size_t)rowg * 128 + colg]);
          ((float*)outv)[(size_t)rowg * 128 + colg] = val + r;
        }
      }
    }
  }
}

extern "C" void kernel_launch(void* const* d_in, const int* in_sizes, int n_in,
                              void* d_out, int out_size, void* d_ws, size_t ws_size,
                              hipStream_t stream) {
  (void)in_sizes; (void)n_in; (void)out_size; (void)ws_size;
  const float* x     = (const float*)d_in[0];
  const float* n1w   = (const float*)d_in[1];
  const float* n1b   = (const float*)d_in[2];
  const float* qkvw  = (const float*)d_in[3];
  const float* qkvb  = (const float*)d_in[4];
  const float* projw = (const float*)d_in[5];
  const float* projb = (const float*)d_in[6];
  const float* ptab  = (const float*)d_in[7];
  const float* w1    = (const float*)d_in[8];
  const float* b1    = (const float*)d_in[9];
  const float* w2    = (const float*)d_in[10];
  const float* b2    = (const float*)d_in[11];
  const float* n2w   = (const float*)d_in[12];
  const float* n2b   = (const float*)d_in[13];
  float* out = (float*)d_out;

  // workspace layout (bytes):
  //   [0,          25690112)   xn   bf16 [wt][128]  (LN1, window order)
  //   [25690112,  102760448)   qkv  bf16 [wt][384]
  //   [102760448, 128450560)   attnout bf16 [wt][128]
  //     u bf16 [tok][512] aliases [25690112, 128450560)  (qkv+attnout dead)
  //   [128450560, 154140672)   x2   bf16 [tok][128]  (residual stream)
  //   [154140672, 179830784)   x2n  bf16 [tok][128]  (LN2 applied)
  //   [179830784, 180224000)   transposed bf16 weights
  char* ws = (char*)d_ws;
  __hip_bfloat16* xn      = (__hip_bfloat16*)ws;
  __hip_bfloat16* qkv     = (__hip_bfloat16*)(ws + 25690112);
  __hip_bfloat16* attnout = (__hip_bfloat16*)(ws + 102760448);
  __hip_bfloat16* u       = (__hip_bfloat16*)(ws + 25690112);
  __hip_bfloat16* x2      = (__hip_bfloat16*)(ws + 128450560);
  __hip_bfloat16* x2n     = (__hip_bfloat16*)(ws + 154140672);
  __hip_bfloat16* wbase   = (__hip_bfloat16*)(ws + 179830784);
  __hip_bfloat16* qkvwT  = wbase;            // [384][128]
  __hip_bfloat16* projwT = wbase + 49152;    // [128][128]
  __hip_bfloat16* w1T    = wbase + 65536;    // [512][128]
  __hip_bfloat16* w2T    = wbase + 131072;   // [128][512]

  prep_all<<<768, 256, 0, stream>>>(qkvw, projw, w1, w2, wbase);
  ln1_apply<<<NTOK / 4, 256, 0, stream>>>(x, n1w, n1b, xn);
  // qkv = xn @ qkv_w + qkv_b  (bf16)
  gemm_mfma<0><<<784 * 3, 256, 0, stream>>>(xn, 128, 3, qkvwT, qkvb,
                                            qkv, 384, nullptr, nullptr, nullptr,
                                            nullptr, nullptr, 128);
  attn_mfma<<<2048, 256, 0, stream>>>(qkv, ptab, attnout);
  // x2[tok] = bf16(x[tok] + attnout @ proj_w + proj_b); x2n = bf16(LN2(row))
  gemm_mfma<4><<<784, 256, 0, stream>>>(attnout, 128, 1, projwT, projb,
                                        x2, 128, x2n, n2w, n2b, x, nullptr, 128);
  // u = gelu(x2n @ w1 + b1)
  gemm_mfma<1><<<784 * 4, 256, 0, stream>>>(x2n, 128, 4, w1T, b1,
                                            (void*)u, 512, nullptr, nullptr, nullptr,
                                            nullptr, nullptr, 128);
  // out = x2 + u @ w2 + b2
  gemm_mfma<3><<<784, 256, 0, stream>>>(u, 512, 1, w2T, b2,
                                        out, 128, nullptr, nullptr, nullptr,
                                        nullptr, x2, 512);
}

// Round 6
// 252.333 us; speedup vs baseline: 3.0031x; 1.0172x over previous
//
#include <hip/hip_runtime.h>
#include <hip/hip_bf16.h>

// Swin block: B=32, HW=56, C=128, WS=7, SS=3, NH=4, HD=32
#define NTOK 100352
#define SCALE_Q 0.17677669529663687f  // 32^-0.5

typedef __bf16 bf16x8 __attribute__((ext_vector_type(8)));
typedef float f32x4 __attribute__((ext_vector_type(4)));
struct bf2 { __hip_bfloat16 x, y; };
struct __align__(8) bh4 { __hip_bfloat16 a, b, c, d; };

// window-token (wt = w*49+n) -> original flat token index in x
__device__ __forceinline__ int wt_to_tok(int wt) {
  int w = wt / 49, n = wt - w * 49;
  int b = w >> 6, wi = w & 63;
  int gh = wi >> 3, gw = wi & 7;
  int r = n / 7, c = n - r * 7;
  int hs = gh * 7 + r + 3; if (hs >= 56) hs -= 56;   // undo roll(-3)
  int ws = gw * 7 + c + 3; if (ws >= 56) ws -= 56;
  return (b * 56 + hs) * 56 + ws;
}

// tanh-approx GELU (overflow-safe)
__device__ __forceinline__ float gelu_fast(float v) {
  float y = 0.7978845608028654f * (v + 0.044715f * v * v * v);
  float ay = fabsf(y);
  float e = __expf(-2.0f * ay);
  float t = (1.0f - e) / (1.0f + e);          // tanh(|y|)
  t = copysignf(t, y);
  return 0.5f * v * (1.0f + t);
}

// all weight transposes + bf16 in one launch
__global__ __launch_bounds__(256) void prep_all(const float* __restrict__ qkvw,
                                                const float* __restrict__ projw,
                                                const float* __restrict__ w1,
                                                const float* __restrict__ w2,
                                                __hip_bfloat16* __restrict__ dst) {
  int i = blockIdx.x * 256 + threadIdx.x;
  float v;
  if (i < 49152) { int n = i >> 7, k = i & 127; v = qkvw[k * 384 + n]; }
  else if (i < 65536) { int j = i - 49152; int n = j >> 7, k = j & 127; v = projw[k * 128 + n]; }
  else if (i < 131072) { int j = i - 65536; int n = j >> 7, k = j & 127; v = w1[k * 512 + n]; }
  else { int j = i - 131072; int n = j / 512, k = j - n * 512; v = w2[k * 128 + n]; }
  dst[i] = __float2bfloat16(v);
}

// xn[wt] = bf16(LN1(x[tok])) — gather to window order fused
__global__ __launch_bounds__(256) void ln1_apply(const float* __restrict__ x,
                                                 const float* __restrict__ nw,
                                                 const float* __restrict__ nb,
                                                 __hip_bfloat16* __restrict__ xn) {
  int wt = blockIdx.x * 4 + (threadIdx.x >> 6);
  int lane = threadIdx.x & 63;
  int tok = wt_to_tok(wt);
  float2 v = *(const float2*)(x + (size_t)tok * 128 + lane * 2);
  float s = v.x + v.y, ss = v.x * v.x + v.y * v.y;
#pragma unroll
  for (int off = 32; off; off >>= 1) {
    s += __shfl_xor(s, off);
    ss += __shfl_xor(ss, off);
  }
  float mu = s * (1.0f / 128.0f);
  float rstd = rsqrtf(ss * (1.0f / 128.0f) - mu * mu + 1e-5f);
  float2 wv = *(const float2*)(nw + lane * 2);
  float2 bv = *(const float2*)(nb + lane * 2);
  bf2 o;
  o.x = __float2bfloat16((v.x - mu) * rstd * wv.x + bv.x);
  o.y = __float2bfloat16((v.y - mu) * rstd * wv.y + bv.y);
  *(bf2*)(xn + (size_t)wt * 128 + lane * 2) = o;
}

// ---------------------------------------------------------------------------
// MFMA attention (unchanged): 1 block = 1 window, wave h = head h.
// ---------------------------------------------------------------------------
__global__ __launch_bounds__(256) void attn_mfma(const __hip_bfloat16* __restrict__ qkv,
                                                 const float* __restrict__ ptab,
                                                 __hip_bfloat16* __restrict__ attnout) {
  __shared__ __align__(16) char lds[4 * 12288];
  const int tid = threadIdx.x;
  const int lane = tid & 63, h = tid >> 6;
  const int w = blockIdx.x;
  const int wi = w & 63, gh = wi >> 3, gw = wi & 7;
  char* Pl = lds + h * 12288;
  char* VTl = Pl + 8192;
  const int lxi = lane & 15, lq = lane >> 4, lg4 = (lane >> 4) * 4;

  const __hip_bfloat16* base = qkv + (size_t)w * 49 * 384 + h * 32;
  __hip_bfloat16* op = attnout + (size_t)w * 49 * 128 + h * 32;

  bf16x8 qa[4], kb[4];
#pragma unroll
  for (int mi = 0; mi < 4; ++mi) {
    int t = mi * 16 + lxi; if (t > 48) t = 48;
    qa[mi] = *(const bf16x8*)(base + (size_t)t * 384 + lq * 8);
    kb[mi] = *(const bf16x8*)(base + (size_t)t * 384 + 128 + lq * 8);
  }
  {
    union { bf16x8 v; __hip_bfloat16 e[8]; } vv[4];
    const __hip_bfloat16* vp = base + (size_t)(lane < 49 ? lane : 0) * 384 + 256;
#pragma unroll
    for (int q = 0; q < 4; ++q) vv[q].v = *(const bf16x8*)(vp + q * 8);
    __hip_bfloat16 z = __float2bfloat16(0.0f);
#pragma unroll
    for (int q = 0; q < 4; ++q)
#pragma unroll
      for (int e = 0; e < 8; ++e) {
        int d = q * 8 + e;
        __hip_bfloat16 val = (lane < 49) ? vv[q].e[e] : z;
        *(__hip_bfloat16*)(VTl + d * 128 + ((lane * 2) ^ ((d & 7) << 4))) = val;
      }
  }

  f32x4 s[4][4] = {};
#pragma unroll
  for (int mi = 0; mi < 4; ++mi)
#pragma unroll
    for (int ni = 0; ni < 4; ++ni)
      s[mi][ni] = __builtin_amdgcn_mfma_f32_16x16x32_bf16(qa[mi], kb[ni], s[mi][ni], 0, 0, 0);

  int rj[4], cj[4], cntj[4], jbad[4];
#pragma unroll
  for (int ni = 0; ni < 4; ++ni) {
    int jc = ni * 16 + lxi;
    jbad[ni] = (jc > 48);
    int jj = jbad[ni] ? 48 : jc;
    rj[ni] = jj / 7; cj[ni] = jj - rj[ni] * 7;
    int hj = gh * 7 + rj[ni], wj = gw * 7 + cj[ni];
    cntj[ni] = (hj < 49 ? 0 : (hj < 53 ? 3 : 6)) + (wj < 49 ? 0 : (wj < 53 ? 1 : 2));
  }
#pragma unroll
  for (int mi = 0; mi < 4; ++mi)
#pragma unroll
    for (int j = 0; j < 4; ++j) {
      int i = mi * 16 + lg4 + j; if (i > 48) i = 48;
      int ri = i / 7, ci = i - ri * 7;
      int hi_ = gh * 7 + ri, wi_ = gw * 7 + ci;
      int cnti = (hi_ < 49 ? 0 : (hi_ < 53 ? 3 : 6)) + (wi_ < 49 ? 0 : (wi_ < 53 ? 1 : 2));
#pragma unroll
      for (int ni = 0; ni < 4; ++ni) {
        float b = ptab[((ri - rj[ni] + 6) * 13 + (ci - cj[ni] + 6)) * 4 + h];
        float val = s[mi][ni][j] * SCALE_Q + b;
        if (cnti != cntj[ni]) val -= 100.0f;
        if (jbad[ni]) val = -1e30f;
        s[mi][ni][j] = val;
      }
    }

#pragma unroll
  for (int mi = 0; mi < 4; ++mi)
#pragma unroll
    for (int j = 0; j < 4; ++j) {
      float m = fmaxf(fmaxf(s[mi][0][j], s[mi][1][j]), fmaxf(s[mi][2][j], s[mi][3][j]));
#pragma unroll
      for (int off = 8; off; off >>= 1) m = fmaxf(m, __shfl_xor(m, off));
      float e[4], sum = 0.0f;
#pragma unroll
      for (int ni = 0; ni < 4; ++ni) { e[ni] = __expf(s[mi][ni][j] - m); sum += e[ni]; }
#pragma unroll
      for (int off = 8; off; off >>= 1) sum += __shfl_xor(sum, off);
      float inv = 1.0f / sum;
#pragma unroll
      for (int ni = 0; ni < 4; ++ni) s[mi][ni][j] = e[ni] * inv;
    }

#pragma unroll
  for (int mi = 0; mi < 4; ++mi)
#pragma unroll
    for (int j = 0; j < 4; ++j) {
      int row = mi * 16 + lg4 + j;
      int sw = (row & 7) << 4;
      char* prow = Pl + row * 128;
#pragma unroll
      for (int ni = 0; ni < 4; ++ni)
        *(__hip_bfloat16*)(prow + (((ni * 16 + lxi) * 2) ^ sw)) =
            __float2bfloat16(s[mi][ni][j]);
    }

  __syncthreads();

  f32x4 o[4][2] = {};
#pragma unroll
  for (int ks = 0; ks < 2; ++ks) {
    bf16x8 pa[4], vb[2];
#pragma unroll
    for (int mi = 0; mi < 4; ++mi) {
      int row = mi * 16 + lxi;
      pa[mi] = *(const bf16x8*)(Pl + row * 128 + ((ks * 64 + lq * 16) ^ ((row & 7) << 4)));
    }
#pragma unroll
    for (int ni = 0; ni < 2; ++ni) {
      int row = ni * 16 + lxi;
      vb[ni] = *(const bf16x8*)(VTl + row * 128 + ((ks * 64 + lq * 16) ^ ((row & 7) << 4)));
    }
#pragma unroll
    for (int mi = 0; mi < 4; ++mi)
#pragma unroll
      for (int ni = 0; ni < 2; ++ni)
        o[mi][ni] = __builtin_amdgcn_mfma_f32_16x16x32_bf16(pa[mi], vb[ni], o[mi][ni], 0, 0, 0);
  }

#pragma unroll
  for (int mi = 0; mi < 4; ++mi)
#pragma unroll
    for (int j = 0; j < 4; ++j) {
      int q = mi * 16 + lg4 + j;
      if (q < 49) {
#pragma unroll
        for (int ni = 0; ni < 2; ++ni)
          op[(size_t)q * 128 + ni * 16 + lxi] = __float2bfloat16(o[mi][ni][j]);
      }
    }
}

// ---------------------------------------------------------------------------
// MFMA bf16 GEMM: 128x128 tile, BK=128, A staged in LDS (32KB), B-fragments
// loaded DIRECTLY from global (weights are L1/L2-resident, [N][K] bf16).
// EPI: 0 = +bias -> bf16 (ldo)
//      4 = proj+LN2 fused: rows are wt; tok=wt_to_tok(row);
//          x2[tok]=bf16(acc+bias+resf[tok]); out2[tok]=bf16(LN(row)*nw+nb)
// ---------------------------------------------------------------------------
template<int EPI>
__global__ __launch_bounds__(256) void gemm_mfma(
    const __hip_bfloat16* __restrict__ A, int lda, int NB,
    const __hip_bfloat16* __restrict__ Wt,
    const float* __restrict__ bias,
    void* __restrict__ outv, int ldo,
    __hip_bfloat16* __restrict__ out2,
    const float* __restrict__ nw, const float* __restrict__ nb,
    const float* __restrict__ resf, int K)
{
  __shared__ __align__(16) char AsB[128 * 256];
  __shared__ float redS[256], redQ[256];
  const int bid = blockIdx.x;
  const int xcd = bid & 7, tt = bid >> 3;
  const int nbk = tt % NB, mseq = tt / NB;
  const int m0 = (mseq * 8 + xcd) * 128, n0 = nbk * 128;
  const int tid = threadIdx.x;
  const int srow = tid >> 1;
  const int scol = (tid & 1) * 64;
  const int lane = tid & 63, wid = tid >> 6;
  const int wm = wid >> 1, wn = wid & 1;
  const int lrow = lane & 15, lq = lane >> 4;

  f32x4 acc[4][4] = {};

  for (int k0 = 0; k0 < K; k0 += 128) {
    {
      const char* ap = (const char*)A + ((size_t)(m0 + srow) * lda + k0 + scol) * 2;
      char* dst = AsB + srow * 256;
      int sw = (srow & 7) << 4;
#pragma unroll
      for (int t = 0; t < 8; ++t) {
        int4 raw = *(const int4*)(ap + t * 16);
        *(int4*)(dst + ((scol * 2 + t * 16) ^ sw)) = raw;
      }
    }
    __syncthreads();
#pragma unroll
    for (int ks = 0; ks < 4; ++ks) {
      int kb = ks * 64 + lq * 16;
      bf16x8 af[4], bfr[4];
#pragma unroll
      for (int mi = 0; mi < 4; ++mi) {
        int r = wm * 64 + mi * 16 + lrow;
        af[mi] = *(const bf16x8*)(AsB + r * 256 + (kb ^ ((r & 7) << 4)));
      }
#pragma unroll
      for (int ni = 0; ni < 4; ++ni) {
        int n = n0 + wn * 64 + ni * 16 + lrow;
        bfr[ni] = *(const bf16x8*)(Wt + (size_t)n * K + k0 + ks * 32 + lq * 8);
      }
#pragma unroll
      for (int mi = 0; mi < 4; ++mi)
#pragma unroll
        for (int ni = 0; ni < 4; ++ni)
          acc[mi][ni] = __builtin_amdgcn_mfma_f32_16x16x32_bf16(af[mi], bfr[ni], acc[mi][ni], 0, 0, 0);
    }
    __syncthreads();
  }

  float bv[4];
#pragma unroll
  for (int ni = 0; ni < 4; ++ni) bv[ni] = bias[n0 + wn * 64 + ni * 16 + lrow];

  if (EPI == 4) {
    // proj + residual + LN2 fused. NB == 1: block owns full 128-wide rows.
    __hip_bfloat16* x2 = (__hip_bfloat16*)outv;
    float nwc[4], nbc[4];
#pragma unroll
    for (int ni = 0; ni < 4; ++ni) {
      int colg = wn * 64 + ni * 16 + lrow;
      nwc[ni] = nw[colg]; nbc[ni] = nb[colg];
    }
    int toks[4][4];
#pragma unroll
    for (int mi = 0; mi < 4; ++mi)
#pragma unroll
      for (int j = 0; j < 4; ++j) {
        int row = wm * 64 + mi * 16 + lq * 4 + j;
        int tok = wt_to_tok(m0 + row);
        toks[mi][j] = tok;
        float s = 0.0f, ss = 0.0f;
#pragma unroll
        for (int ni = 0; ni < 4; ++ni) {
          int colg = wn * 64 + ni * 16 + lrow;
          float val = acc[mi][ni][j] + bv[ni] + resf[(size_t)tok * 128 + colg];
          x2[(size_t)tok * 128 + colg] = __float2bfloat16(val);
          acc[mi][ni][j] = val;
          s += val; ss += val * val;
        }
#pragma unroll
        for (int off = 8; off; off >>= 1) {
          s += __shfl_xor(s, off);
          ss += __shfl_xor(ss, off);
        }
        if (lrow == 0) { redS[row * 2 + wn] = s; redQ[row * 2 + wn] = ss; }
      }
    __syncthreads();
#pragma unroll
    for (int mi = 0; mi < 4; ++mi)
#pragma unroll
      for (int j = 0; j < 4; ++j) {
        int row = wm * 64 + mi * 16 + lq * 4 + j;
        float s = redS[row * 2] + redS[row * 2 + 1];
        float ss = redQ[row * 2] + redQ[row * 2 + 1];
        float mu = s * (1.0f / 128.0f);
        float rstd = rsqrtf(ss * (1.0f / 128.0f) - mu * mu + 1e-5f);
        int tok = toks[mi][j];
#pragma unroll
        for (int ni = 0; ni < 4; ++ni) {
          int colg = wn * 64 + ni * 16 + lrow;
          float xnv = (acc[mi][ni][j] - mu) * rstd * nwc[ni] + nbc[ni];
          out2[(size_t)tok * 128 + colg] = __float2bfloat16(xnv);
        }
      }
    return;
  }

#pragma unroll
  for (int mi = 0; mi < 4; ++mi) {
#pragma unroll
    for (int j = 0; j < 4; ++j) {
      int rowg = m0 + wm * 64 + mi * 16 + lq * 4 + j;
#pragma unroll
      for (int ni = 0; ni < 4; ++ni) {
        int colg = n0 + wn * 64 + ni * 16 + lrow;
        float val = acc[mi][ni][j] + bv[ni];
        ((__hip_bfloat16*)outv)[(size_t)rowg * ldo + colg] = __float2bfloat16(val);
      }
    }
  }
}

// ---------------------------------------------------------------------------
// Fused MLP: out[tok] = x2[tok] + gelu(x2n @ W1 + b1) @ W2 + b2.
// 128 tokens/block, 4 hidden chunks of 128. The hidden activation never
// touches HBM: chunk h computed via OPERAND-SWAPPED mfma (D = [hd][m]) so the
// transpose packs into contiguous 8B LDS writes; W1/W2 B-fragments come
// directly from global (weights L1/L2-resident).
// ---------------------------------------------------------------------------
__global__ __launch_bounds__(256) void mlp_fused(
    const __hip_bfloat16* __restrict__ x2n,  // [NTOK][128]
    const __hip_bfloat16* __restrict__ w1T,  // [512][128]
    const float* __restrict__ b1,
    const __hip_bfloat16* __restrict__ w2T,  // [128][512]
    const float* __restrict__ b2,
    const __hip_bfloat16* __restrict__ x2,   // [NTOK][128] residual
    float* __restrict__ out)                 // [NTOK][128]
{
  __shared__ __align__(16) char AsB[128 * 256];
  __shared__ __align__(16) char Hs[128 * 256];
  const int m0 = blockIdx.x * 128;
  const int tid = threadIdx.x;
  const int srow = tid >> 1, scol = (tid & 1) * 64;
  const int lane = tid & 63, wid = tid >> 6;
  const int wm = wid >> 1, wn = wid & 1;
  const int lrow = lane & 15, lq = lane >> 4;

  // stage A = x2n tile (swizzled)
  {
    const char* ap = (const char*)x2n + ((size_t)(m0 + srow) * 128 + scol) * 2;
    char* dst = AsB + srow * 256;
    int sw = (srow & 7) << 4;
#pragma unroll
    for (int t = 0; t < 8; ++t) {
      int4 raw = *(const int4*)(ap + t * 16);
      *(int4*)(dst + ((scol * 2 + t * 16) ^ sw)) = raw;
    }
  }
  __syncthreads();

  f32x4 oacc[4][4] = {};

  for (int c = 0; c < 4; ++c) {
    // ---- gemm1 (swapped): hT[hd][m] = W1c-rows x A-rows ----
    f32x4 hacc[4][4] = {};
#pragma unroll
    for (int ks = 0; ks < 4; ++ks) {
      int kb = ks * 64 + lq * 16;
      bf16x8 wf[4], afr[4];
#pragma unroll
      for (int mi = 0; mi < 4; ++mi) {
        int hd = c * 128 + wm * 64 + mi * 16 + lrow;
        wf[mi] = *(const bf16x8*)(w1T + (size_t)hd * 128 + ks * 32 + lq * 8);
      }
#pragma unroll
      for (int ni = 0; ni < 4; ++ni) {
        int r = wn * 64 + ni * 16 + lrow;
        afr[ni] = *(const bf16x8*)(AsB + r * 256 + (kb ^ ((r & 7) << 4)));
      }
#pragma unroll
      for (int mi = 0; mi < 4; ++mi)
#pragma unroll
        for (int ni = 0; ni < 4; ++ni)
          hacc[mi][ni] = __builtin_amdgcn_mfma_f32_16x16x32_bf16(wf[mi], afr[ni], hacc[mi][ni], 0, 0, 0);
    }
    __syncthreads();   // previous chunk's Hs fully consumed
    // gelu(+b1) and write h to Hs[m][hd_local] — 4 consecutive hd pack to 8B
#pragma unroll
    for (int mi = 0; mi < 4; ++mi) {
      int hdb = wm * 64 + mi * 16 + lq * 4;       // hd_local base (j=0..3)
      float b1v[4];
#pragma unroll
      for (int j = 0; j < 4; ++j) b1v[j] = b1[c * 128 + hdb + j];
#pragma unroll
      for (int ni = 0; ni < 4; ++ni) {
        int m_ = wn * 64 + ni * 16 + lrow;
        bh4 hv;
        hv.a = __float2bfloat16(gelu_fast(hacc[mi][ni][0] + b1v[0]));
        hv.b = __float2bfloat16(gelu_fast(hacc[mi][ni][1] + b1v[1]));
        hv.c = __float2bfloat16(gelu_fast(hacc[mi][ni][2] + b1v[2]));
        hv.d = __float2bfloat16(gelu_fast(hacc[mi][ni][3] + b1v[3]));
        *(bh4*)(Hs + m_ * 256 + ((hdb * 2) ^ ((m_ & 7) << 4))) = hv;
      }
    }
    __syncthreads();
    // ---- gemm2: out += H @ W2c ----
#pragma unroll
    for (int ks = 0; ks < 4; ++ks) {
      int kb = ks * 64 + lq * 16;
      bf16x8 hf[4], w2f[4];
#pragma unroll
      for (int mi = 0; mi < 4; ++mi) {
        int r = wm * 64 + mi * 16 + lrow;
        hf[mi] = *(const bf16x8*)(Hs + r * 256 + (kb ^ ((r & 7) << 4)));
      }
#pragma unroll
      for (int ni = 0; ni < 4; ++ni) {
        int n = wn * 64 + ni * 16 + lrow;
        w2f[ni] = *(const bf16x8*)(w2T + (size_t)n * 512 + c * 128 + ks * 32 + lq * 8);
      }
#pragma unroll
      for (int mi = 0; mi < 4; ++mi)
#pragma unroll
        for (int ni = 0; ni < 4; ++ni)
          oacc[mi][ni] = __builtin_amdgcn_mfma_f32_16x16x32_bf16(hf[mi], w2f[ni], oacc[mi][ni], 0, 0, 0);
    }
  }

  // epilogue: + b2 + residual -> fp32 out
  float bv[4];
#pragma unroll
  for (int ni = 0; ni < 4; ++ni) bv[ni] = b2[wn * 64 + ni * 16 + lrow];
#pragma unroll
  for (int mi = 0; mi < 4; ++mi)
#pragma unroll
    for (int j = 0; j < 4; ++j) {
      int row = m0 + wm * 64 + mi * 16 + lq * 4 + j;
#pragma unroll
      for (int ni = 0; ni < 4; ++ni) {
        int col = wn * 64 + ni * 16 + lrow;
        float r = __bfloat162float(x2[(size_t)row * 128 + col]);
        out[(size_t)row * 128 + col] = oacc[mi][ni][j] + bv[ni] + r;
      }
    }
}

extern "C" void kernel_launch(void* const* d_in, const int* in_sizes, int n_in,
                              void* d_out, int out_size, void* d_ws, size_t ws_size,
                              hipStream_t stream) {
  (void)in_sizes; (void)n_in; (void)out_size; (void)ws_size;
  const float* x     = (const float*)d_in[0];
  const float* n1w   = (const float*)d_in[1];
  const float* n1b   = (const float*)d_in[2];
  const float* qkvw  = (const float*)d_in[3];
  const float* qkvb  = (const float*)d_in[4];
  const float* projw = (const float*)d_in[5];
  const float* projb = (const float*)d_in[6];
  const float* ptab  = (const float*)d_in[7];
  const float* w1    = (const float*)d_in[8];
  const float* b1    = (const float*)d_in[9];
  const float* w2    = (const float*)d_in[10];
  const float* b2    = (const float*)d_in[11];
  const float* n2w   = (const float*)d_in[12];
  const float* n2b   = (const float*)d_in[13];
  float* out = (float*)d_out;

  // workspace layout (bytes):
  //   [0,          25690112)   xn   bf16 [wt][128]  (LN1, window order)
  //   [25690112,  102760448)   qkv  bf16 [wt][384]
  //   [102760448, 128450560)   attnout bf16 [wt][128]
  //   [128450560, 154140672)   x2   bf16 [tok][128]  (residual stream)
  //   [154140672, 179830784)   x2n  bf16 [tok][128]  (LN2 applied)
  //   [179830784, 180224000)   transposed bf16 weights
  char* ws = (char*)d_ws;
  __hip_bfloat16* xn      = (__hip_bfloat16*)ws;
  __hip_bfloat16* qkv     = (__hip_bfloat16*)(ws + 25690112);
  __hip_bfloat16* attnout = (__hip_bfloat16*)(ws + 102760448);
  __hip_bfloat16* x2      = (__hip_bfloat16*)(ws + 128450560);
  __hip_bfloat16* x2n     = (__hip_bfloat16*)(ws + 154140672);
  __hip_bfloat16* wbase   = (__hip_bfloat16*)(ws + 179830784);
  __hip_bfloat16* qkvwT  = wbase;            // [384][128]
  __hip_bfloat16* projwT = wbase + 49152;    // [128][128]
  __hip_bfloat16* w1T    = wbase + 65536;    // [512][128]
  __hip_bfloat16* w2T    = wbase + 131072;   // [128][512]

  prep_all<<<768, 256, 0, stream>>>(qkvw, projw, w1, w2, wbase);
  ln1_apply<<<NTOK / 4, 256, 0, stream>>>(x, n1w, n1b, xn);
  // qkv = xn @ qkv_w + qkv_b  (bf16)
  gemm_mfma<0><<<784 * 3, 256, 0, stream>>>(xn, 128, 3, qkvwT, qkvb,
                                            qkv, 384, nullptr, nullptr, nullptr,
                                            nullptr, 128);
  attn_mfma<<<2048, 256, 0, stream>>>(qkv, ptab, attnout);
  // x2[tok] = bf16(x[tok] + attnout @ proj_w + proj_b); x2n = bf16(LN2(row))
  gemm_mfma<4><<<784, 256, 0, stream>>>(attnout, 128, 1, projwT, projb,
                                        x2, 128, x2n, n2w, n2b, x, 128);
  // out = x2 + gelu(x2n @ w1 + b1) @ w2 + b2   (hidden never hits HBM)
  mlp_fused<<<784, 256, 0, stream>>>(x2n, w1T, b1, w2T, b2, x2, out);
}